// Round 11
// baseline (1725.191 us; speedup 1.0000x reference)
//
#include <hip/hip_runtime.h>
#include <cstdint>
#include <cstddef>
#include <type_traits>

#define NA 50000
#define NT 100000
#define FA 128
#define FT 64
#define HID 128
#define OUTF 64
#define HEADS 8
#define E1 500000
#define E2 250000
#define NTOT (2*NT + 2*NA)          // concatenated dst-node space [at|ta|aa|tt]
#define ETOT (2*E1 + 2*E2)          // concatenated edge space
#define NSH 8                       // CSR build shards (== XCDs heuristic)
#define NDB 64                      // degree buckets for agg wave-shape sort

typedef __attribute__((ext_vector_type(8))) short short8;
typedef __attribute__((ext_vector_type(4))) float f32x4;

static __device__ __forceinline__ ushort f2b(float f) {  // f32 -> bf16 RNE
  unsigned int u = __float_as_uint(f);
  return (ushort)((u + 0x7fffu + ((u >> 16) & 1u)) >> 16);
}
static __device__ __forceinline__ float b2f(ushort b) {
  return __uint_as_float(((unsigned int)b) << 16);
}
static __device__ __forceinline__ float u2f_lo(unsigned int u) {
  return __uint_as_float(u << 16);
}
static __device__ __forceinline__ float u2f_hi(unsigned int u) {
  return __uint_as_float(u & 0xffff0000u);
}

// ============== shared GEMM building blocks (XOR-swizzled LDS) =============
template<int KK>
static __device__ __forceinline__ int lidx(int row, int off) {
  return row * KK + (off ^ ((row & 7) << 3));
}

template<int KK, int M>
static __device__ __forceinline__ void stageB(const float* __restrict__ W,
                                              ushort* __restrict__ Bls)
{
  constexpr int TPC = 256 / M;          // threads per col
  constexpr int CH  = KK / TPC;         // k-chunk per thread
  constexpr int BL  = (CH < 16) ? CH : 16;
  int t = threadIdx.x;
  int col = t % M;
  int k0 = (t / M) * CH;
  const float* Wp = W + col;
#pragma unroll
  for (int b = 0; b < CH; b += BL) {
    float v[BL];
#pragma unroll
    for (int i = 0; i < BL; i++) v[i] = Wp[(size_t)(k0 + b + i) * M];
#pragma unroll
    for (int q = 0; q < BL / 8; q++) {
      union { ushort u[8]; uint4 x; } p;
#pragma unroll
      for (int i = 0; i < 8; i++) p.u[i] = f2b(v[q * 8 + i]);
      *reinterpret_cast<uint4*>(&Bls[lidx<KK>(col, k0 + b + q * 8)]) = p.x;
    }
  }
}

template<int KK, typename AT>
struct ARegs {
  float4 f[std::is_same<AT, float>::value ? KK / 16 : 1];
  uint4  u[std::is_same<AT, float>::value ? 1 : KK / 32];
};

template<int KK, typename AT>
static __device__ __forceinline__ void loadA(const AT* __restrict__ A, int N,
                                             int row0, ARegs<KK, AT>& R)
{
  int t = threadIdx.x;
  int arow = t >> 2, ac0 = (t & 3) * (KK / 4);
  int row = row0 + arow;
  bool ok = row < N;
  const AT* Ap = A + (size_t)row * KK + ac0;
  if constexpr (std::is_same<AT, float>::value) {
#pragma unroll
    for (int j = 0; j < KK / 16; j++)
      R.f[j] = ok ? *reinterpret_cast<const float4*>(Ap + j * 4)
                  : make_float4(0.f, 0.f, 0.f, 0.f);
  } else {
#pragma unroll
    for (int j = 0; j < KK / 32; j++)
      R.u[j] = ok ? *reinterpret_cast<const uint4*>(Ap + j * 8)
                  : make_uint4(0, 0, 0, 0);
  }
}

template<int KK, typename AT>
static __device__ __forceinline__ void writeA(const ARegs<KK, AT>& R,
                                              ushort* __restrict__ Als)
{
  int t = threadIdx.x;
  int arow = t >> 2, ac0 = (t & 3) * (KK / 4);
#pragma unroll
  for (int j = 0; j < KK / 32; j++) {
    uint4 w;
    if constexpr (std::is_same<AT, float>::value) {
      union { ushort u[8]; uint4 x; } p;
      float4 a0 = R.f[2 * j], a1 = R.f[2 * j + 1];
      p.u[0] = f2b(a0.x); p.u[1] = f2b(a0.y); p.u[2] = f2b(a0.z); p.u[3] = f2b(a0.w);
      p.u[4] = f2b(a1.x); p.u[5] = f2b(a1.y); p.u[6] = f2b(a1.z); p.u[7] = f2b(a1.w);
      w = p.x;
    } else {
      w = R.u[j];
    }
    *reinterpret_cast<uint4*>(&Als[lidx<KK>(arow, ac0 + j * 8)]) = w;
  }
}

template<int KK, int NCT>
static __device__ __forceinline__ void mfma_tile(const ushort* __restrict__ Als,
    const ushort* __restrict__ Bls, f32x4* acc)
{
  int lane = threadIdx.x & 63, w = threadIdx.x >> 6;
  int l15 = lane & 15, l4 = lane >> 4;
#pragma unroll
  for (int ks = 0; ks < KK / 32; ks++) {
    short8 af = *reinterpret_cast<const short8*>(
        &Als[lidx<KK>(16 * w + l15, ks * 32 + l4 * 8)]);
#pragma unroll
    for (int n = 0; n < NCT; n++) {
      short8 bf = *reinterpret_cast<const short8*>(
          &Bls[lidx<KK>(16 * n + l15, ks * 32 + l4 * 8)]);
      acc[n] = __builtin_amdgcn_mfma_f32_16x16x32_bf16(af, bf, acc[n], 0, 0, 0);
    }
  }
}

// ====== z-projection GEMM (full M per block, TPB row-tiles, W staged once) =
template<int NV, int DD, int KK, int M, int TPB, typename AT>
__global__ __launch_bounds__(256) void zgemm_k(
    const AT* __restrict__ A, const float* __restrict__ W,
    const float* __restrict__ bias,
    const float* __restrict__ v0, const float* __restrict__ v1,
    const float* __restrict__ v2, const float* __restrict__ v3,
    float* __restrict__ o0, float* __restrict__ o1,
    float* __restrict__ o2, float* __restrict__ o3,
    ushort* __restrict__ Cb, int N)
{
  constexpr int NCT = M / 16;
  __shared__ __align__(16) ushort Bls[M * KK];
  __shared__ __align__(16) ushort Als[64 * KK];
  int t = threadIdx.x, w = t >> 6, lane = t & 63;
  int l15 = lane & 15, l4 = lane >> 4;
  int ntiles = (N + 63) >> 6;
  int tile0 = blockIdx.x * TPB;
  int nt = min(TPB, ntiles - tile0);

  stageB<KK, M>(W, Bls);
  ARegs<KK, AT> R;
  loadA<KK, AT>(A, N, tile0 * 64, R);

  float bv[NCT], aw0[NCT], aw1[NCT], aw2[NCT], aw3[NCT];
#pragma unroll
  for (int n = 0; n < NCT; n++) {
    int col = 16 * n + l15;
    bv[n] = bias[col];
    int head = (DD == 16) ? n : (n * 2 + (l15 >> 3));
    int vi = head * DD + (l15 & (DD - 1));
    aw0[n] = v0[vi];
    aw1[n] = (NV > 1) ? v1[vi] : 0.f;
    aw2[n] = (NV > 2) ? v2[vi] : 0.f;
    aw3[n] = (NV > 3) ? v3[vi] : 0.f;
  }

  for (int i = 0; i < nt; i++) {
    int row0 = (tile0 + i) * 64;
    __syncthreads();
    writeA<KK, AT>(R, Als);
    __syncthreads();
    if (i + 1 < nt) loadA<KK, AT>(A, N, row0 + 64, R);
    f32x4 acc[NCT];
#pragma unroll
    for (int n = 0; n < NCT; n++) acc[n] = (f32x4){0.f, 0.f, 0.f, 0.f};
    mfma_tile<KK, NCT>(Als, Bls, acc);

#pragma unroll
    for (int n = 0; n < NCT; n++) {
      int col = 16 * n + l15;
      int head = (DD == 16) ? n : (n * 2 + (l15 >> 3));
#pragma unroll
      for (int r = 0; r < 4; r++) {
        int row = row0 + 16 * w + l4 * 4 + r;
        float v = acc[n][r] + bv[n];
        if (row < N) Cb[(size_t)row * M + col] = f2b(v);
        float a0 = v * aw0[n], a1 = v * aw1[n], a2 = v * aw2[n], a3 = v * aw3[n];
#pragma unroll
        for (int o = 1; o < DD; o <<= 1) {
          a0 += __shfl_xor(a0, o);
          if (NV > 1) a1 += __shfl_xor(a1, o);
          if (NV > 2) a2 += __shfl_xor(a2, o);
          if (NV > 3) a3 += __shfl_xor(a3, o);
        }
        if ((l15 & (DD - 1)) == 0 && row < N) {
          o0[(size_t)row * 8 + head] = a0;
          if (NV > 1) o1[(size_t)row * 8 + head] = a1;
          if (NV > 2) o2[(size_t)row * 8 + head] = a2;
          if (NV > 3) o3[(size_t)row * 8 + head] = a3;
        }
      }
    }
  }
}

// ====== multi-task score GEMM: atomicAdd(scp[t], sum tanh(C+b)*q) ==========
template<int KK, int M, int TPB>
__global__ __launch_bounds__(256) void score_k(
    const ushort* __restrict__ A0, const ushort* __restrict__ A1,
    const ushort* __restrict__ A2, const ushort* __restrict__ A3,
    const float* __restrict__ W, const float* __restrict__ bias,
    const float* __restrict__ qv, float* __restrict__ scp,
    int4 cumB, int4 Ns)
{
  constexpr int NCT = M / 16;
  __shared__ __align__(16) ushort Bls[M * KK];
  __shared__ __align__(16) ushort Als[64 * KK];
  __shared__ float red[4];
  int b = blockIdx.x;
  int tsk, bbase, N; const ushort* A;
  if      (b < cumB.x) { tsk = 0; bbase = 0;      N = Ns.x; A = A0; }
  else if (b < cumB.y) { tsk = 1; bbase = cumB.x; N = Ns.y; A = A1; }
  else if (b < cumB.z) { tsk = 2; bbase = cumB.y; N = Ns.z; A = A2; }
  else                 { tsk = 3; bbase = cumB.z; N = Ns.w; A = A3; }
  int t = threadIdx.x, w = t >> 6, lane = t & 63;
  int l15 = lane & 15, l4 = lane >> 4;
  int ntiles = (N + 63) >> 6;
  int tile0 = (b - bbase) * TPB;
  int nt = min(TPB, ntiles - tile0);

  stageB<KK, M>(W, Bls);
  ARegs<KK, ushort> R;
  loadA<KK, ushort>(A, N, tile0 * 64, R);

  float bb[NCT], qb[NCT];
#pragma unroll
  for (int n = 0; n < NCT; n++) {
    int col = 16 * n + l15;
    bb[n] = bias[col]; qb[n] = qv[col];
  }

  float ls = 0.f;
  for (int i = 0; i < nt; i++) {
    int row0 = (tile0 + i) * 64;
    __syncthreads();
    writeA<KK, ushort>(R, Als);
    __syncthreads();
    if (i + 1 < nt) loadA<KK, ushort>(A, N, row0 + 64, R);
    f32x4 acc[NCT];
#pragma unroll
    for (int n = 0; n < NCT; n++) acc[n] = (f32x4){0.f, 0.f, 0.f, 0.f};
    mfma_tile<KK, NCT>(Als, Bls, acc);
#pragma unroll
    for (int n = 0; n < NCT; n++) {
#pragma unroll
      for (int r = 0; r < 4; r++) {
        int row = row0 + 16 * w + l4 * 4 + r;
        if (row < N) ls += tanhf(acc[n][r] + bb[n]) * qb[n];
      }
    }
  }
#pragma unroll
  for (int o = 32; o > 0; o >>= 1) ls += __shfl_xor(ls, o);
  if (lane == 0) red[w] = ls;
  __syncthreads();
  if (t == 0) atomicAdd(&scp[tsk], red[0] + red[1] + red[2] + red[3]);
}

// ============== XCD-sharded CSR build + compaction =========================
__global__ void hist4_sh(const int* __restrict__ d0, const int* __restrict__ d1,
    const int* __restrict__ d2, const int* __restrict__ d3,
    int* __restrict__ cnt8, float* __restrict__ scp)
{
  if (blockIdx.x == 0 && threadIdx.x < 8) scp[threadIdx.x] = 0.f;
  int e = blockIdx.x * 256 + threadIdx.x;
  int sh = blockIdx.x & (NSH - 1);
  int d;
  if      (e < E1)          d = d0[e];
  else if (e < 2*E1)        d = d1[e - E1] + NT;
  else if (e < 2*E1 + E2)   d = d2[e - 2*E1] + NT + NA;
  else if (e < ETOT)        d = d3[e - 2*E1 - E2] + NT + 2*NA;
  else return;
  atomicAdd(&cnt8[sh * NTOT + d], 1);
}

__global__ void scatter_sh(const int* __restrict__ s0, const int* __restrict__ d0,
    const int* __restrict__ s1, const int* __restrict__ d1,
    const int* __restrict__ s2, const int* __restrict__ d2,
    const int* __restrict__ s3, const int* __restrict__ d3,
    int* __restrict__ cur8, int* __restrict__ ssh)
{
  int e = blockIdx.x * 256 + threadIdx.x;
  int sh = blockIdx.x & (NSH - 1);
  int d, s;
  if      (e < E1)          { d = d0[e];                           s = s0[e]; }
  else if (e < 2*E1)        { d = d1[e - E1] + NT;                 s = s1[e - E1]; }
  else if (e < 2*E1 + E2)   { d = d2[e - 2*E1] + NT + NA;          s = s2[e - 2*E1]; }
  else if (e < ETOT)        { d = d3[e - 2*E1 - E2] + NT + 2*NA;   s = s3[e - 2*E1 - E2]; }
  else return;
  int p = atomicAdd(&cur8[sh * NTOT + d], 1);
  ssh[p] = s;
}

// merge each node's 8 shard-segments into the contiguous final CSR order
__global__ void compact_k(const int* __restrict__ rp8, const int* __restrict__ rp,
    const int* __restrict__ ssh, int* __restrict__ ssrc)
{
  int g = blockIdx.x * 256 + threadIdx.x;
  if (g >= NTOT) return;
  int w = rp[g];
#pragma unroll
  for (int s = 0; s < NSH; s++) {
    int b0 = rp8[s * NTOT + g], b1 = rp8[s * NTOT + g + 1];
    for (int e = b0; e < b1; e++) ssrc[w++] = ssh[e];
  }
}

// per-block inclusive scan (256 thr x 8) of in -> rp1 (=rp+1); totals -> bsum
__global__ __launch_bounds__(256) void scan_blk(const int* __restrict__ in,
    int* __restrict__ rp1, int* __restrict__ bsum, int n)
{
  __shared__ int sh[256];
  int base = blockIdx.x * 2048;
  int t = threadIdx.x;
  int v[8]; int s = 0;
#pragma unroll
  for (int k = 0; k < 8; k++) {
    int i = base + t * 8 + k;
    v[k] = (i < n) ? in[i] : 0; s += v[k];
  }
  sh[t] = s; __syncthreads();
  for (int o = 1; o < 256; o <<= 1) {
    int x = (t >= o) ? sh[t - o] : 0;
    __syncthreads(); sh[t] += x; __syncthreads();
  }
  int run = (t == 0) ? 0 : sh[t - 1];
  if (t == 255 && bsum) bsum[blockIdx.x] = sh[255];
#pragma unroll
  for (int k = 0; k < 8; k++) {
    int i = base + t * 8 + k;
    run += v[k];
    if (i < n) rp1[i] = run;
  }
}

// like scan_blk, but element i = sum over 8 shards of cnt8[s*NTOT+i]
__global__ __launch_bounds__(256) void scan_blk_sum8(const int* __restrict__ cnt8,
    int* __restrict__ rp1, int* __restrict__ bsum, int n)
{
  __shared__ int sh[256];
  int base = blockIdx.x * 2048;
  int t = threadIdx.x;
  int v[8]; int s = 0;
#pragma unroll
  for (int k = 0; k < 8; k++) {
    int i = base + t * 8 + k;
    int x = 0;
    if (i < n) {
#pragma unroll
      for (int sh2 = 0; sh2 < NSH; sh2++) x += cnt8[sh2 * NTOT + i];
    }
    v[k] = x; s += x;
  }
  sh[t] = s; __syncthreads();
  for (int o = 1; o < 256; o <<= 1) {
    int x = (t >= o) ? sh[t - o] : 0;
    __syncthreads(); sh[t] += x; __syncthreads();
  }
  int run = (t == 0) ? 0 : sh[t - 1];
  if (t == 255 && bsum) bsum[blockIdx.x] = sh[255];
#pragma unroll
  for (int k = 0; k < 8; k++) {
    int i = base + t * 8 + k;
    run += v[k];
    if (i < n) rp1[i] = run;
  }
}

// two independent in-place single-block scans in one dispatch
__global__ __launch_bounds__(256) void scan_two(int* __restrict__ b0, int n0,
                                                int* __restrict__ b1, int n1)
{
  __shared__ int sh[256];
  int* arr = blockIdx.x ? b1 : b0;
  int n = blockIdx.x ? n1 : n0;
  int t = threadIdx.x;
  int v[8]; int s = 0;
#pragma unroll
  for (int k = 0; k < 8; k++) {
    int i = t * 8 + k;
    v[k] = (i < n) ? arr[i] : 0; s += v[k];
  }
  sh[t] = s; __syncthreads();
  for (int o = 1; o < 256; o <<= 1) {
    int x = (t >= o) ? sh[t - o] : 0;
    __syncthreads(); sh[t] += x; __syncthreads();
  }
  int run = (t == 0) ? 0 : sh[t - 1];
#pragma unroll
  for (int k = 0; k < 8; k++) {
    int i = t * 8 + k;
    run += v[k];
    if (i < n) arr[i] = run;
  }
}

// merged: add block-offsets for rp8/cur8 (n8 elems) AND rp (n1 elems)
__global__ void scan_addM(int* __restrict__ rp8, int* __restrict__ cur8,
    const int* __restrict__ bsA, int n8,
    int* __restrict__ rp, const int* __restrict__ bsB, int n1)
{
  int i = blockIdx.x * blockDim.x + threadIdx.x;
  if (i == 0) { rp8[0] = 0; cur8[0] = 0; rp[0] = 0; }
  if (i < n8) {
    int blk = i >> 11;
    int base = blk ? bsA[blk - 1] : 0;
    int v = rp8[i + 1] + base;
    rp8[i + 1] = v;
    if (i + 1 < n8) cur8[i + 1] = v;
  }
  if (i < n1) {
    int blk = i >> 11;
    int base = blk ? bsB[blk - 1] : 0;
    rp[i + 1] += base;
  }
}

// ============ degree-bucket sort (wave-shape equalization for agg) =========
// perm laid out segment-contiguous [at|ta|aa|tt], same bases as node space;
// perm[segbase + k] = local node index, ordered by clamped degree.
static __device__ __forceinline__ void seg_of(int g, int& segbase) {
  if      (g < NT)          segbase = 0;
  else if (g < NT + NA)     segbase = NT;
  else if (g < NT + 2*NA)   segbase = NT + NA;
  else                      segbase = NT + 2*NA;
}
static __device__ __forceinline__ int segid_of(int g) {
  if      (g < NT)          return 0;
  else if (g < NT + NA)     return 1;
  else if (g < NT + 2*NA)   return 2;
  else                      return 3;
}

__global__ void deg_hist(const int* __restrict__ rp, int* __restrict__ dh)
{
  int g = blockIdx.x * 256 + threadIdx.x;
  if (g >= NTOT) return;
  int deg = min(rp[g + 1] - rp[g], NDB - 1);
  atomicAdd(&dh[segid_of(g) * NDB + deg], 1);
}

__global__ void deg_scan(int* __restrict__ dh)   // in-place exclusive per seg
{
  int s = threadIdx.x;
  if (s < 4) {
    int run = 0;
    for (int d = 0; d < NDB; d++) {
      int c = dh[s * NDB + d]; dh[s * NDB + d] = run; run += c;
    }
  }
}

__global__ void deg_scat(const int* __restrict__ rp, int* __restrict__ dcur,
                         int* __restrict__ perm)
{
  int g = blockIdx.x * 256 + threadIdx.x;
  if (g >= NTOT) return;
  int segbase; seg_of(g, segbase);
  int deg = min(rp[g + 1] - rp[g], NDB - 1);
  int pos = atomicAdd(&dcur[segid_of(g) * NDB + deg], 1);
  perm[segbase + pos] = g - segbase;
}

// =============== atomic-free GAT aggregation, node per lane-group ==========
// Nodes assigned to lane-groups in degree-sorted order (perm) so the NPW
// groups of a wave have near-equal edge-loop trip counts (kills exec-mask
// divergence). Per-node math and edge order unchanged -> bitwise identical.
struct AggTask {
  int g0, Nd;
  const float* als; const float* ald;
  const ushort* z;  ushort* out;
};

template<int F>
__global__ __launch_bounds__(256) void agg_multi(const int* __restrict__ rp,
    const int* __restrict__ ssrc, const int* __restrict__ perm,
    AggTask C0A, AggTask C0B, AggTask C1A, AggTask C1B,
    int split0, int split1, int btot)
{
  constexpr int LPN = (F == 128) ? 16 : 8;   // lanes per node
  constexpr int NPW = 64 / LPN;              // nodes per wave
  int b = blockIdx.x;
  int cls = (b >> 2) & 1;                    // XCD class
  int lb = (b >> 3) * 4 + (b & 3);           // linear block index within class
  if (lb >= btot) return;
  AggTask T;
  if (cls == 0) { if (lb < split0) T = C0A; else { T = C0B; lb -= split0; } }
  else          { if (lb < split1) T = C1A; else { T = C1B; lb -= split1; } }
  int wv = threadIdx.x >> 6, lane = threadIdx.x & 63;
  int grp = lane / LPN, lg = lane % LPN;
  int idx = (lb * 4 + wv) * NPW + grp;
  if (idx >= T.Nd) return;
  int n = perm[T.g0 + idx];
  int g = T.g0 + n;
  int start = rp[g], end = rp[g + 1];
  int hh = (F == 128) ? (lg >> 1) : lg;      // head owning this lane's feats
  float ad_h = T.ald[(size_t)n * 8 + hh];

  float den = 0.f;
  float acc[8] = {};
  int e = start;
  for (; e + 1 < end; e += 2) {
    int sn0 = ssrc[e], sn1 = ssrc[e + 1];
    uint4 z0 = *reinterpret_cast<const uint4*>(T.z + (size_t)sn0 * F + lg * 8);
    uint4 z1 = *reinterpret_cast<const uint4*>(T.z + (size_t)sn1 * F + lg * 8);
    float a0 = T.als[(size_t)sn0 * 8 + hh] + ad_h;
    float a1 = T.als[(size_t)sn1 * 8 + hh] + ad_h;
    a0 = a0 > 0.f ? a0 : 0.2f * a0;
    a1 = a1 > 0.f ? a1 : 0.2f * a1;
    float p0 = __expf(fminf(a0, 30.f));
    float p1 = __expf(fminf(a1, 30.f));
    den += p0 + p1;
    acc[0] = fmaf(p0, u2f_lo(z0.x), fmaf(p1, u2f_lo(z1.x), acc[0]));
    acc[1] = fmaf(p0, u2f_hi(z0.x), fmaf(p1, u2f_hi(z1.x), acc[1]));
    acc[2] = fmaf(p0, u2f_lo(z0.y), fmaf(p1, u2f_lo(z1.y), acc[2]));
    acc[3] = fmaf(p0, u2f_hi(z0.y), fmaf(p1, u2f_hi(z1.y), acc[3]));
    acc[4] = fmaf(p0, u2f_lo(z0.z), fmaf(p1, u2f_lo(z1.z), acc[4]));
    acc[5] = fmaf(p0, u2f_hi(z0.z), fmaf(p1, u2f_hi(z1.z), acc[5]));
    acc[6] = fmaf(p0, u2f_lo(z0.w), fmaf(p1, u2f_lo(z1.w), acc[6]));
    acc[7] = fmaf(p0, u2f_hi(z0.w), fmaf(p1, u2f_hi(z1.w), acc[7]));
  }
  if (e < end) {
    int sn = ssrc[e];
    uint4 zv = *reinterpret_cast<const uint4*>(T.z + (size_t)sn * F + lg * 8);
    float a = T.als[(size_t)sn * 8 + hh] + ad_h;
    a = a > 0.f ? a : 0.2f * a;
    float p = __expf(fminf(a, 30.f));
    den += p;
    acc[0] = fmaf(p, u2f_lo(zv.x), acc[0]);
    acc[1] = fmaf(p, u2f_hi(zv.x), acc[1]);
    acc[2] = fmaf(p, u2f_lo(zv.y), acc[2]);
    acc[3] = fmaf(p, u2f_hi(zv.y), acc[3]);
    acc[4] = fmaf(p, u2f_lo(zv.z), acc[4]);
    acc[5] = fmaf(p, u2f_hi(zv.z), acc[5]);
    acc[6] = fmaf(p, u2f_lo(zv.w), acc[6]);
    acc[7] = fmaf(p, u2f_hi(zv.w), acc[7]);
  }
  float inv = 1.f / fmaxf(den, 1e-16f);
  unsigned int pk[4];
#pragma unroll
  for (int k2 = 0; k2 < 4; k2++)
    pk[k2] = (unsigned int)f2b(fmaxf(acc[2*k2] * inv, 0.f))
           | ((unsigned int)f2b(fmaxf(acc[2*k2+1] * inv, 0.f)) << 16);
  *reinterpret_cast<uint4*>(T.out + (size_t)n * F + lg * 8)
      = make_uint4(pk[0], pk[1], pk[2], pk[3]);
}

// ---- semantic softmax (K=2) combine + LayerNorm + ReLU, 2 tasks, F=128 ----
__global__ __launch_bounds__(256) void combine2_k(
    const ushort* __restrict__ o00, const ushort* __restrict__ o01,
    const float* __restrict__ sc0, float invn0, ushort* __restrict__ out0, int N0,
    const ushort* __restrict__ o10, const ushort* __restrict__ o11,
    const float* __restrict__ sc1, float invn1, ushort* __restrict__ out1, int N1,
    const float* __restrict__ g, const float* __restrict__ bb)
{
  int c1 = (N0 + 3) / 4;
  int b = blockIdx.x;
  const ushort *o0, *o1; const float* sc; float invn; ushort* outp; int N, lb;
  if (b < c1) { o0=o00; o1=o01; sc=sc0; invn=invn0; outp=out0; N=N0; lb=b; }
  else        { o0=o10; o1=o11; sc=sc1; invn=invn1; outp=out1; N=N1; lb=b-c1; }
  int wv = threadIdx.x >> 6, lane = threadIdx.x & 63;
  int n = lb * 4 + wv;
  if (n >= N) return;
  float s0 = sc[0] * invn, s1 = sc[1] * invn;
  float mx = fmaxf(s0, s1);
  float e0 = __expf(s0 - mx), e1 = __expf(s1 - mx);
  float w0 = e0 / (e0 + e1), w1 = e1 / (e0 + e1);
  float x[2];
#pragma unroll
  for (int jj = 0; jj < 2; jj++) {
    int idx = lane + 64 * jj;
    x[jj] = w0 * b2f(o0[(size_t)n * 128 + idx]) + w1 * b2f(o1[(size_t)n * 128 + idx]);
  }
  float sum = x[0] + x[1];
#pragma unroll
  for (int o = 32; o > 0; o >>= 1) sum += __shfl_xor(sum, o);
  float mu = sum / 128.f;
  float vs = 0.f;
#pragma unroll
  for (int jj = 0; jj < 2; jj++) { float dd = x[jj] - mu; vs = fmaf(dd, dd, vs); }
#pragma unroll
  for (int o = 32; o > 0; o >>= 1) vs += __shfl_xor(vs, o);
  float rstd = rsqrtf(vs / 128.f + 1e-5f);
#pragma unroll
  for (int jj = 0; jj < 2; jj++) {
    int idx = lane + 64 * jj;
    float y = (x[jj] - mu) * rstd * g[idx] + bb[idx];
    outp[(size_t)n * 128 + idx] = f2b(fmaxf(y, 0.f));
  }
}

// ---- layer-2 combine + LN + ReLU + final linear [64]->[2], F=64 ----------
__global__ __launch_bounds__(256) void combine_final_k(
    const ushort* __restrict__ o0, const ushort* __restrict__ o1,
    const float* __restrict__ sc, float invn,
    const float* __restrict__ g, const float* __restrict__ bb,
    const float* __restrict__ lw, const float* __restrict__ lb,
    float* __restrict__ outp, int N)
{
  int wv = threadIdx.x >> 6, lane = threadIdx.x & 63;
  int n = blockIdx.x * 4 + wv;
  if (n >= N) return;
  float s0 = sc[0] * invn, s1 = sc[1] * invn;
  float mx = fmaxf(s0, s1);
  float e0 = __expf(s0 - mx), e1 = __expf(s1 - mx);
  float w0 = e0 / (e0 + e1), w1 = e1 / (e0 + e1);
  float x = w0 * b2f(o0[(size_t)n * 64 + lane]) + w1 * b2f(o1[(size_t)n * 64 + lane]);
  float sum = x;
#pragma unroll
  for (int o = 32; o > 0; o >>= 1) sum += __shfl_xor(sum, o);
  float mu = sum / 64.f;
  float dd = x - mu;
  float vs = dd * dd;
#pragma unroll
  for (int o = 32; o > 0; o >>= 1) vs += __shfl_xor(vs, o);
  float rstd = rsqrtf(vs / 64.f + 1e-5f);
  float y = fmaxf((x - mu) * rstd * g[lane] + bb[lane], 0.f);
  float p0 = y * lw[lane * 2 + 0];
  float p1 = y * lw[lane * 2 + 1];
#pragma unroll
  for (int o = 32; o > 0; o >>= 1) { p0 += __shfl_xor(p0, o); p1 += __shfl_xor(p1, o); }
  if (lane == 0) {
    outp[(size_t)n * 2 + 0] = p0 + lb[0];
    outp[(size_t)n * 2 + 1] = p1 + lb[1];
  }
}

extern "C" void kernel_launch(void* const* d_in, const int* in_sizes, int n_in,
                              void* d_out, int out_size, void* d_ws, size_t ws_size,
                              hipStream_t stream)
{
  (void)in_sizes; (void)n_in; (void)out_size;
  const float* x_a = (const float*)d_in[0];
  const float* x_t = (const float*)d_in[1];
  const int* eat_s = (const int*)d_in[2];
  const int* eat_d = (const int*)d_in[3];
  const int* eta_s = (const int*)d_in[4];
  const int* eta_d = (const int*)d_in[5];
  const int* eaa_s = (const int*)d_in[6];
  const int* eaa_d = (const int*)d_in[7];
  const int* ett_s = (const int*)d_in[8];
  const int* ett_d = (const int*)d_in[9];
  const float* W_a1 = (const float*)d_in[10]; const float* b_a1 = (const float*)d_in[11];
  const float* W_t1 = (const float*)d_in[12]; const float* b_t1 = (const float*)d_in[13];
  const float* as_at1 = (const float*)d_in[14]; const float* ad_at1 = (const float*)d_in[15];
  const float* as_ta1 = (const float*)d_in[16]; const float* ad_ta1 = (const float*)d_in[17];
  const float* as_aa1 = (const float*)d_in[18]; const float* ad_aa1 = (const float*)d_in[19];
  const float* as_tt1 = (const float*)d_in[20]; const float* ad_tt1 = (const float*)d_in[21];
  const float* k1_W = (const float*)d_in[22]; const float* k1_b = (const float*)d_in[23];
  const float* q1   = (const float*)d_in[24];
  const float* W_a2 = (const float*)d_in[25]; const float* b_a2 = (const float*)d_in[26];
  const float* W_t2 = (const float*)d_in[27]; const float* b_t2 = (const float*)d_in[28];
  const float* as_ta2 = (const float*)d_in[31]; const float* ad_ta2 = (const float*)d_in[32];
  const float* as_aa2 = (const float*)d_in[33]; const float* ad_aa2 = (const float*)d_in[34];
  const float* k2_W = (const float*)d_in[37]; const float* k2_b = (const float*)d_in[38];
  const float* q2   = (const float*)d_in[39];
  const float* ln1_g = (const float*)d_in[40]; const float* ln1_b = (const float*)d_in[41];
  const float* ln2_g = (const float*)d_in[42]; const float* ln2_b = (const float*)d_in[43];
  const float* lin_W = (const float*)d_in[44]; const float* lin_b = (const float*)d_in[45];

  char* ws = (char*)d_ws;
  size_t off = 0;
  auto alloc = [&](size_t bytes) {
    size_t o = off; off += (bytes + 255) & ~(size_t)255; return o;
  };
  size_t ZA1 = alloc((size_t)NA * HID * 2);     // bf16 z_a; layer2 za2 aliases
  size_t ZT1 = alloc((size_t)NT * HID * 2);     // bf16 z_t; layer2 zt2 aliases
  size_t OTA = alloc((size_t)NA * HID * 2);     // bf16 o_ta -> xa1 in-place
  size_t OAA = alloc((size_t)NA * HID * 2);     // bf16 o_aa; L2: ota2|oaa2 alias
  size_t OAT = alloc((size_t)NT * HID * 2);     // bf16 o_at -> xt1 in-place
  size_t OTT = alloc((size_t)NT * HID * 2);
  size_t A_AS_AT = alloc((size_t)NA * 8 * 4);
  size_t A_AD_TA = alloc((size_t)NA * 8 * 4);
  size_t A_AS_AA = alloc((size_t)NA * 8 * 4);
  size_t A_AD_AA = alloc((size_t)NA * 8 * 4);
  size_t A_T_D_AT = alloc((size_t)NT * 8 * 4);
  size_t A_T_S_TA = alloc((size_t)NT * 8 * 4);
  size_t A_T_S_TT = alloc((size_t)NT * 8 * 4);
  size_t A_T_D_TT = alloc((size_t)NT * 8 * 4);
  // sharded CSR build + compacted final CSR
  size_t RP8  = alloc(((size_t)NSH * NTOT + 1) * 4);
  size_t CUR8 = alloc((size_t)NSH * NTOT * 4);  // doubles as sharded hist
  size_t SSH  = alloc((size_t)ETOT * 4);
  size_t RP   = alloc((size_t)(NTOT + 1) * 4);
  size_t SS   = alloc((size_t)ETOT * 4);
  size_t BSM  = alloc(2048 * 4);
  size_t BSM2 = alloc(256 * 4);
  size_t DH   = alloc(4 * NDB * 4);             // degree hist / cursors
  size_t PERM = alloc((size_t)NTOT * 4);        // degree-sorted node perm
  size_t SC   = alloc(256);                     // 6 score accumulators
  if (off > ws_size) return;                    // fail visibly

  ushort* za1 = (ushort*)(ws + ZA1);
  ushort* zt1 = (ushort*)(ws + ZT1);
  ushort* ota = (ushort*)(ws + OTA);
  ushort* oaa = (ushort*)(ws + OAA);
  ushort* oat = (ushort*)(ws + OAT);
  ushort* ott = (ushort*)(ws + OTT);
  float* aASAT = (float*)(ws + A_AS_AT);
  float* aADTA = (float*)(ws + A_AD_TA);
  float* aASAA = (float*)(ws + A_AS_AA);
  float* aADAA = (float*)(ws + A_AD_AA);
  float* aTDAT = (float*)(ws + A_T_D_AT);
  float* aTSTA = (float*)(ws + A_T_S_TA);
  float* aTSTT = (float*)(ws + A_T_S_TT);
  float* aTDTT = (float*)(ws + A_T_D_TT);
  int* rp8  = (int*)(ws + RP8);
  int* cur8 = (int*)(ws + CUR8);
  int* ssh  = (int*)(ws + SSH);
  int* rp   = (int*)(ws + RP);
  int* ssrc = (int*)(ws + SS);
  int* bsum = (int*)(ws + BSM);
  int* bsum2= (int*)(ws + BSM2);
  int* dh   = (int*)(ws + DH);
  int* perm = (int*)(ws + PERM);
  float* scp = (float*)(ws + SC);
  // layer-2 aliases
  ushort* za2 = za1;                                   // [NA,64] bf16
  ushort* zt2 = zt1;                                   // [NT,64] bf16
  ushort* ota2 = oaa;                                  // [NA,64] bf16
  ushort* oaa2 = (ushort*)(ws + OAA + (size_t)NA * OUTF * 2);  // [NA,64] bf16

  const int TA = (NA + 63) / 64, TT = (NT + 63) / 64;  // row tiles
  const int EBL = (ETOT + 255) / 256;
  const int SCN8 = NSH * NTOT;
  const int SBL8 = (SCN8 + 2047) / 2048;
  const int SBL1 = (NTOT + 2047) / 2048;
  const int NBL = (NTOT + 255) / 256;

  // ---- sharded CSR build + compact + degree sort ----
  hipMemsetAsync(cur8, 0, (size_t)SCN8 * 4, stream);
  hipMemsetAsync(dh, 0, 4 * NDB * 4, stream);
  hist4_sh<<<EBL, 256, 0, stream>>>(eat_d, eta_d, eaa_d, ett_d, cur8, scp);
  scan_blk<<<SBL8, 256, 0, stream>>>(cur8, rp8 + 1, bsum, SCN8);
  scan_blk_sum8<<<SBL1, 256, 0, stream>>>(cur8, rp + 1, bsum2, NTOT);
  scan_two<<<2, 256, 0, stream>>>(bsum, SBL8, bsum2, SBL1);
  scan_addM<<<(SCN8 + 255) / 256, 256, 0, stream>>>(rp8, cur8, bsum, SCN8,
                                                    rp, bsum2, NTOT);
  scatter_sh<<<EBL, 256, 0, stream>>>(eat_s, eat_d, eta_s, eta_d,
                                      eaa_s, eaa_d, ett_s, ett_d, cur8, ssh);
  compact_k<<<NBL, 256, 0, stream>>>(rp8, rp, ssh, ssrc);
  deg_hist<<<NBL, 256, 0, stream>>>(rp, dh);
  deg_scan<<<1, 64, 0, stream>>>(dh);
  deg_scat<<<NBL, 256, 0, stream>>>(rp, dh, perm);

  // ============ Layer 1 ============
  zgemm_k<4,16,FA,HID,2,float><<<(TA+1)/2,256,0,stream>>>(x_a, W_a1, b_a1,
      as_at1, ad_ta1, as_aa1, ad_aa1, aASAT, aADTA, aASAA, aADAA, za1, NA);
  zgemm_k<4,16,FT,HID,4,float><<<(TT+3)/4,256,0,stream>>>(x_t, W_t1, b_t1,
      ad_at1, as_ta1, as_tt1, ad_tt1, aTDAT, aTSTA, aTSTT, aTDTT, zt1, NT);
  {
    const int BT = (NT + 15) / 16, BA = (NA + 15) / 16;
    const int btot = BT + BA;
    const int grid = ((btot + 3) / 4) * 8;
    AggTask Tat{0,        NT, aASAT, aTDAT, za1, oat};
    AggTask Taa{NT+NA,    NA, aASAA, aADAA, za1, oaa};
    AggTask Tta{NT,       NA, aTSTA, aADTA, zt1, ota};
    AggTask Ttt{NT+2*NA,  NT, aTSTT, aTDTT, zt1, ott};
    agg_multi<128><<<grid, 256, 0, stream>>>(rp, ssrc, perm,
        Tat, Taa, Tta, Ttt, BT, BA, btot);
  }
  {
    const int bA = (TA + 3) / 4, bT = (TT + 3) / 4;
    score_k<HID,HID,4><<<2*bA + 2*bT, 256, 0, stream>>>(ota, oaa, oat, ott,
        k1_W, k1_b, q1, scp,
        make_int4(bA, 2*bA, 2*bA + bT, 2*bA + 2*bT),
        make_int4(NA, NA, NT, NT));
  }
  combine2_k<<<(NA/4) + (NT/4), 256, 0, stream>>>(
      ota, oaa, scp + 0, 1.f/NA, ota, NA,
      oat, ott, scp + 2, 1.f/NT, oat, NT, ln1_g, ln1_b);

  // ============ Layer 2 (only the address path feeds the output) ============
  zgemm_k<3,8,HID,OUTF,2,ushort><<<(TA+1)/2,256,0,stream>>>(ota, W_a2, b_a2,
      ad_ta2, as_aa2, ad_aa2, nullptr, aADTA, aASAA, aADAA, nullptr, za2, NA);
  zgemm_k<1,8,HID,OUTF,4,ushort><<<(TT+3)/4,256,0,stream>>>(oat, W_t2, b_t2,
      as_ta2, nullptr, nullptr, nullptr, aTSTA, nullptr, nullptr, nullptr, zt2, NT);
  {
    const int BA2 = (NA + 31) / 32;
    const int grid = ((BA2 + 3) / 4) * 8;
    AggTask Taa2{NT+NA, NA, aASAA, aADAA, za2, oaa2};
    AggTask Tta2{NT,    NA, aTSTA, aADTA, zt2, ota2};
    agg_multi<64><<<grid, 256, 0, stream>>>(rp, ssrc, perm,
        Taa2, Taa2, Tta2, Tta2, BA2, BA2, BA2);
  }
  {
    const int bA = (TA + 3) / 4;
    score_k<OUTF,OUTF,4><<<2*bA, 256, 0, stream>>>(ota2, oaa2, ota2, ota2,
        k2_W, k2_b, q2, scp + 4,
        make_int4(bA, 2*bA, 2*bA, 2*bA),
        make_int4(NA, NA, NA, NA));
  }
  combine_final_k<<<NA/4, 256, 0, stream>>>(ota2, oaa2, scp + 4, 1.f/NA,
      ln2_g, ln2_b, lin_W, lin_b, (float*)d_out, NA);
}

// Round 12
// 543.338 us; speedup vs baseline: 3.1752x; 3.1752x over previous
//
#include <hip/hip_runtime.h>
#include <cstdint>
#include <cstddef>
#include <type_traits>

#define NA 50000
#define NT 100000
#define FA 128
#define FT 64
#define HID 128
#define OUTF 64
#define HEADS 8
#define E1 500000
#define E2 250000
#define NTOT (2*NT + 2*NA)          // concatenated dst-node space [at|ta|aa|tt]
#define ETOT (2*E1 + 2*E2)          // concatenated edge space
#define NSH 8                       // CSR build shards (== XCDs heuristic)
#define NDB 64                      // degree buckets for agg wave-shape sort
#define NBL ((NTOT + 255) / 256)    // blocks over node space (1172)
#define NDEG (4 * NDB * NBL)        // blocked degree-histogram elements

typedef __attribute__((ext_vector_type(8))) short short8;
typedef __attribute__((ext_vector_type(4))) float f32x4;

static __device__ __forceinline__ ushort f2b(float f) {  // f32 -> bf16 RNE
  unsigned int u = __float_as_uint(f);
  return (ushort)((u + 0x7fffu + ((u >> 16) & 1u)) >> 16);
}
static __device__ __forceinline__ float b2f(ushort b) {
  return __uint_as_float(((unsigned int)b) << 16);
}
static __device__ __forceinline__ float u2f_lo(unsigned int u) {
  return __uint_as_float(u << 16);
}
static __device__ __forceinline__ float u2f_hi(unsigned int u) {
  return __uint_as_float(u & 0xffff0000u);
}

// ============== shared GEMM building blocks (XOR-swizzled LDS) =============
template<int KK>
static __device__ __forceinline__ int lidx(int row, int off) {
  return row * KK + (off ^ ((row & 7) << 3));
}

template<int KK, int M>
static __device__ __forceinline__ void stageB(const float* __restrict__ W,
                                              ushort* __restrict__ Bls)
{
  constexpr int TPC = 256 / M;          // threads per col
  constexpr int CH  = KK / TPC;         // k-chunk per thread
  constexpr int BL  = (CH < 16) ? CH : 16;
  int t = threadIdx.x;
  int col = t % M;
  int k0 = (t / M) * CH;
  const float* Wp = W + col;
#pragma unroll
  for (int b = 0; b < CH; b += BL) {
    float v[BL];
#pragma unroll
    for (int i = 0; i < BL; i++) v[i] = Wp[(size_t)(k0 + b + i) * M];
#pragma unroll
    for (int q = 0; q < BL / 8; q++) {
      union { ushort u[8]; uint4 x; } p;
#pragma unroll
      for (int i = 0; i < 8; i++) p.u[i] = f2b(v[q * 8 + i]);
      *reinterpret_cast<uint4*>(&Bls[lidx<KK>(col, k0 + b + q * 8)]) = p.x;
    }
  }
}

template<int KK, typename AT>
struct ARegs {
  float4 f[std::is_same<AT, float>::value ? KK / 16 : 1];
  uint4  u[std::is_same<AT, float>::value ? 1 : KK / 32];
};

template<int KK, typename AT>
static __device__ __forceinline__ void loadA(const AT* __restrict__ A, int N,
                                             int row0, ARegs<KK, AT>& R)
{
  int t = threadIdx.x;
  int arow = t >> 2, ac0 = (t & 3) * (KK / 4);
  int row = row0 + arow;
  bool ok = row < N;
  const AT* Ap = A + (size_t)row * KK + ac0;
  if constexpr (std::is_same<AT, float>::value) {
#pragma unroll
    for (int j = 0; j < KK / 16; j++)
      R.f[j] = ok ? *reinterpret_cast<const float4*>(Ap + j * 4)
                  : make_float4(0.f, 0.f, 0.f, 0.f);
  } else {
#pragma unroll
    for (int j = 0; j < KK / 32; j++)
      R.u[j] = ok ? *reinterpret_cast<const uint4*>(Ap + j * 8)
                  : make_uint4(0, 0, 0, 0);
  }
}

template<int KK, typename AT>
static __device__ __forceinline__ void writeA(const ARegs<KK, AT>& R,
                                              ushort* __restrict__ Als)
{
  int t = threadIdx.x;
  int arow = t >> 2, ac0 = (t & 3) * (KK / 4);
#pragma unroll
  for (int j = 0; j < KK / 32; j++) {
    uint4 w;
    if constexpr (std::is_same<AT, float>::value) {
      union { ushort u[8]; uint4 x; } p;
      float4 a0 = R.f[2 * j], a1 = R.f[2 * j + 1];
      p.u[0] = f2b(a0.x); p.u[1] = f2b(a0.y); p.u[2] = f2b(a0.z); p.u[3] = f2b(a0.w);
      p.u[4] = f2b(a1.x); p.u[5] = f2b(a1.y); p.u[6] = f2b(a1.z); p.u[7] = f2b(a1.w);
      w = p.x;
    } else {
      w = R.u[j];
    }
    *reinterpret_cast<uint4*>(&Als[lidx<KK>(arow, ac0 + j * 8)]) = w;
  }
}

template<int KK, int NCT>
static __device__ __forceinline__ void mfma_tile(const ushort* __restrict__ Als,
    const ushort* __restrict__ Bls, f32x4* acc)
{
  int lane = threadIdx.x & 63, w = threadIdx.x >> 6;
  int l15 = lane & 15, l4 = lane >> 4;
#pragma unroll
  for (int ks = 0; ks < KK / 32; ks++) {
    short8 af = *reinterpret_cast<const short8*>(
        &Als[lidx<KK>(16 * w + l15, ks * 32 + l4 * 8)]);
#pragma unroll
    for (int n = 0; n < NCT; n++) {
      short8 bf = *reinterpret_cast<const short8*>(
          &Bls[lidx<KK>(16 * n + l15, ks * 32 + l4 * 8)]);
      acc[n] = __builtin_amdgcn_mfma_f32_16x16x32_bf16(af, bf, acc[n], 0, 0, 0);
    }
  }
}

// ====== z-projection GEMM (full M per block, TPB row-tiles, W staged once) =
template<int NV, int DD, int KK, int M, int TPB, typename AT>
__global__ __launch_bounds__(256) void zgemm_k(
    const AT* __restrict__ A, const float* __restrict__ W,
    const float* __restrict__ bias,
    const float* __restrict__ v0, const float* __restrict__ v1,
    const float* __restrict__ v2, const float* __restrict__ v3,
    float* __restrict__ o0, float* __restrict__ o1,
    float* __restrict__ o2, float* __restrict__ o3,
    ushort* __restrict__ Cb, int N)
{
  constexpr int NCT = M / 16;
  __shared__ __align__(16) ushort Bls[M * KK];
  __shared__ __align__(16) ushort Als[64 * KK];
  int t = threadIdx.x, w = t >> 6, lane = t & 63;
  int l15 = lane & 15, l4 = lane >> 4;
  int ntiles = (N + 63) >> 6;
  int tile0 = blockIdx.x * TPB;
  int nt = min(TPB, ntiles - tile0);

  stageB<KK, M>(W, Bls);
  ARegs<KK, AT> R;
  loadA<KK, AT>(A, N, tile0 * 64, R);

  float bv[NCT], aw0[NCT], aw1[NCT], aw2[NCT], aw3[NCT];
#pragma unroll
  for (int n = 0; n < NCT; n++) {
    int col = 16 * n + l15;
    bv[n] = bias[col];
    int head = (DD == 16) ? n : (n * 2 + (l15 >> 3));
    int vi = head * DD + (l15 & (DD - 1));
    aw0[n] = v0[vi];
    aw1[n] = (NV > 1) ? v1[vi] : 0.f;
    aw2[n] = (NV > 2) ? v2[vi] : 0.f;
    aw3[n] = (NV > 3) ? v3[vi] : 0.f;
  }

  for (int i = 0; i < nt; i++) {
    int row0 = (tile0 + i) * 64;
    __syncthreads();
    writeA<KK, AT>(R, Als);
    __syncthreads();
    if (i + 1 < nt) loadA<KK, AT>(A, N, row0 + 64, R);
    f32x4 acc[NCT];
#pragma unroll
    for (int n = 0; n < NCT; n++) acc[n] = (f32x4){0.f, 0.f, 0.f, 0.f};
    mfma_tile<KK, NCT>(Als, Bls, acc);

#pragma unroll
    for (int n = 0; n < NCT; n++) {
      int col = 16 * n + l15;
      int head = (DD == 16) ? n : (n * 2 + (l15 >> 3));
#pragma unroll
      for (int r = 0; r < 4; r++) {
        int row = row0 + 16 * w + l4 * 4 + r;
        float v = acc[n][r] + bv[n];
        if (row < N) Cb[(size_t)row * M + col] = f2b(v);
        float a0 = v * aw0[n], a1 = v * aw1[n], a2 = v * aw2[n], a3 = v * aw3[n];
#pragma unroll
        for (int o = 1; o < DD; o <<= 1) {
          a0 += __shfl_xor(a0, o);
          if (NV > 1) a1 += __shfl_xor(a1, o);
          if (NV > 2) a2 += __shfl_xor(a2, o);
          if (NV > 3) a3 += __shfl_xor(a3, o);
        }
        if ((l15 & (DD - 1)) == 0 && row < N) {
          o0[(size_t)row * 8 + head] = a0;
          if (NV > 1) o1[(size_t)row * 8 + head] = a1;
          if (NV > 2) o2[(size_t)row * 8 + head] = a2;
          if (NV > 3) o3[(size_t)row * 8 + head] = a3;
        }
      }
    }
  }
}

// ====== multi-task score GEMM: atomicAdd(scp[t], sum tanh(C+b)*q) ==========
template<int KK, int M, int TPB>
__global__ __launch_bounds__(256) void score_k(
    const ushort* __restrict__ A0, const ushort* __restrict__ A1,
    const ushort* __restrict__ A2, const ushort* __restrict__ A3,
    const float* __restrict__ W, const float* __restrict__ bias,
    const float* __restrict__ qv, float* __restrict__ scp,
    int4 cumB, int4 Ns)
{
  constexpr int NCT = M / 16;
  __shared__ __align__(16) ushort Bls[M * KK];
  __shared__ __align__(16) ushort Als[64 * KK];
  __shared__ float red[4];
  int b = blockIdx.x;
  int tsk, bbase, N; const ushort* A;
  if      (b < cumB.x) { tsk = 0; bbase = 0;      N = Ns.x; A = A0; }
  else if (b < cumB.y) { tsk = 1; bbase = cumB.x; N = Ns.y; A = A1; }
  else if (b < cumB.z) { tsk = 2; bbase = cumB.y; N = Ns.z; A = A2; }
  else                 { tsk = 3; bbase = cumB.z; N = Ns.w; A = A3; }
  int t = threadIdx.x, w = t >> 6, lane = t & 63;
  int l15 = lane & 15, l4 = lane >> 4;
  int ntiles = (N + 63) >> 6;
  int tile0 = (b - bbase) * TPB;
  int nt = min(TPB, ntiles - tile0);

  stageB<KK, M>(W, Bls);
  ARegs<KK, ushort> R;
  loadA<KK, ushort>(A, N, tile0 * 64, R);

  float bb[NCT], qb[NCT];
#pragma unroll
  for (int n = 0; n < NCT; n++) {
    int col = 16 * n + l15;
    bb[n] = bias[col]; qb[n] = qv[col];
  }

  float ls = 0.f;
  for (int i = 0; i < nt; i++) {
    int row0 = (tile0 + i) * 64;
    __syncthreads();
    writeA<KK, ushort>(R, Als);
    __syncthreads();
    if (i + 1 < nt) loadA<KK, ushort>(A, N, row0 + 64, R);
    f32x4 acc[NCT];
#pragma unroll
    for (int n = 0; n < NCT; n++) acc[n] = (f32x4){0.f, 0.f, 0.f, 0.f};
    mfma_tile<KK, NCT>(Als, Bls, acc);
#pragma unroll
    for (int n = 0; n < NCT; n++) {
#pragma unroll
      for (int r = 0; r < 4; r++) {
        int row = row0 + 16 * w + l4 * 4 + r;
        if (row < N) ls += tanhf(acc[n][r] + bb[n]) * qb[n];
      }
    }
  }
#pragma unroll
  for (int o = 32; o > 0; o >>= 1) ls += __shfl_xor(ls, o);
  if (lane == 0) red[w] = ls;
  __syncthreads();
  if (t == 0) atomicAdd(&scp[tsk], red[0] + red[1] + red[2] + red[3]);
}

// ============== XCD-sharded CSR build + compaction =========================
__global__ void hist4_sh(const int* __restrict__ d0, const int* __restrict__ d1,
    const int* __restrict__ d2, const int* __restrict__ d3,
    int* __restrict__ cnt8, float* __restrict__ scp)
{
  if (blockIdx.x == 0 && threadIdx.x < 8) scp[threadIdx.x] = 0.f;
  int e = blockIdx.x * 256 + threadIdx.x;
  int sh = blockIdx.x & (NSH - 1);
  int d;
  if      (e < E1)          d = d0[e];
  else if (e < 2*E1)        d = d1[e - E1] + NT;
  else if (e < 2*E1 + E2)   d = d2[e - 2*E1] + NT + NA;
  else if (e < ETOT)        d = d3[e - 2*E1 - E2] + NT + 2*NA;
  else return;
  atomicAdd(&cnt8[sh * NTOT + d], 1);
}

__global__ void scatter_sh(const int* __restrict__ s0, const int* __restrict__ d0,
    const int* __restrict__ s1, const int* __restrict__ d1,
    const int* __restrict__ s2, const int* __restrict__ d2,
    const int* __restrict__ s3, const int* __restrict__ d3,
    int* __restrict__ cur8, int* __restrict__ ssh)
{
  int e = blockIdx.x * 256 + threadIdx.x;
  int sh = blockIdx.x & (NSH - 1);
  int d, s;
  if      (e < E1)          { d = d0[e];                           s = s0[e]; }
  else if (e < 2*E1)        { d = d1[e - E1] + NT;                 s = s1[e - E1]; }
  else if (e < 2*E1 + E2)   { d = d2[e - 2*E1] + NT + NA;          s = s2[e - 2*E1]; }
  else if (e < ETOT)        { d = d3[e - 2*E1 - E2] + NT + 2*NA;   s = s3[e - 2*E1 - E2]; }
  else return;
  int p = atomicAdd(&cur8[sh * NTOT + d], 1);
  ssh[p] = s;
}

// merge each node's 8 shard-segments into the contiguous final CSR order
__global__ void compact_k(const int* __restrict__ rp8, const int* __restrict__ rp,
    const int* __restrict__ ssh, int* __restrict__ ssrc)
{
  int g = blockIdx.x * 256 + threadIdx.x;
  if (g >= NTOT) return;
  int w = rp[g];
#pragma unroll
  for (int s = 0; s < NSH; s++) {
    int b0 = rp8[s * NTOT + g], b1 = rp8[s * NTOT + g + 1];
    for (int e = b0; e < b1; e++) ssrc[w++] = ssh[e];
  }
}

// per-block inclusive scan (256 thr x 8) of in -> rp1 (=rp+1); totals -> bsum
__global__ __launch_bounds__(256) void scan_blk(const int* __restrict__ in,
    int* __restrict__ rp1, int* __restrict__ bsum, int n)
{
  __shared__ int sh[256];
  int base = blockIdx.x * 2048;
  int t = threadIdx.x;
  int v[8]; int s = 0;
#pragma unroll
  for (int k = 0; k < 8; k++) {
    int i = base + t * 8 + k;
    v[k] = (i < n) ? in[i] : 0; s += v[k];
  }
  sh[t] = s; __syncthreads();
  for (int o = 1; o < 256; o <<= 1) {
    int x = (t >= o) ? sh[t - o] : 0;
    __syncthreads(); sh[t] += x; __syncthreads();
  }
  int run = (t == 0) ? 0 : sh[t - 1];
  if (t == 255 && bsum) bsum[blockIdx.x] = sh[255];
#pragma unroll
  for (int k = 0; k < 8; k++) {
    int i = base + t * 8 + k;
    run += v[k];
    if (i < n) rp1[i] = run;
  }
}

// like scan_blk, but element i = sum over 8 shards of cnt8[s*NTOT+i]
__global__ __launch_bounds__(256) void scan_blk_sum8(const int* __restrict__ cnt8,
    int* __restrict__ rp1, int* __restrict__ bsum, int n)
{
  __shared__ int sh[256];
  int base = blockIdx.x * 2048;
  int t = threadIdx.x;
  int v[8]; int s = 0;
#pragma unroll
  for (int k = 0; k < 8; k++) {
    int i = base + t * 8 + k;
    int x = 0;
    if (i < n) {
#pragma unroll
      for (int sh2 = 0; sh2 < NSH; sh2++) x += cnt8[sh2 * NTOT + i];
    }
    v[k] = x; s += x;
  }
  sh[t] = s; __syncthreads();
  for (int o = 1; o < 256; o <<= 1) {
    int x = (t >= o) ? sh[t - o] : 0;
    __syncthreads(); sh[t] += x; __syncthreads();
  }
  int run = (t == 0) ? 0 : sh[t - 1];
  if (t == 255 && bsum) bsum[blockIdx.x] = sh[255];
#pragma unroll
  for (int k = 0; k < 8; k++) {
    int i = base + t * 8 + k;
    run += v[k];
    if (i < n) rp1[i] = run;
  }
}

// up to two independent in-place single-block scans in one dispatch
__global__ __launch_bounds__(256) void scan_two(int* __restrict__ b0, int n0,
                                                int* __restrict__ b1, int n1)
{
  __shared__ int sh[256];
  int* arr = blockIdx.x ? b1 : b0;
  int n = blockIdx.x ? n1 : n0;
  if (n <= 0) return;
  int t = threadIdx.x;
  int v[8]; int s = 0;
#pragma unroll
  for (int k = 0; k < 8; k++) {
    int i = t * 8 + k;
    v[k] = (i < n) ? arr[i] : 0; s += v[k];
  }
  sh[t] = s; __syncthreads();
  for (int o = 1; o < 256; o <<= 1) {
    int x = (t >= o) ? sh[t - o] : 0;
    __syncthreads(); sh[t] += x; __syncthreads();
  }
  int run = (t == 0) ? 0 : sh[t - 1];
#pragma unroll
  for (int k = 0; k < 8; k++) {
    int i = t * 8 + k;
    run += v[k];
    if (i < n) arr[i] = run;
  }
}

// merged: add block-offsets for rp8/cur8 (n8 elems) AND rp (n1 elems)
__global__ void scan_addM(int* __restrict__ rp8, int* __restrict__ cur8,
    const int* __restrict__ bsA, int n8,
    int* __restrict__ rp, const int* __restrict__ bsB, int n1)
{
  int i = blockIdx.x * blockDim.x + threadIdx.x;
  if (i == 0) { rp8[0] = 0; cur8[0] = 0; rp[0] = 0; }
  if (i < n8) {
    int blk = i >> 11;
    int base = blk ? bsA[blk - 1] : 0;
    int v = rp8[i + 1] + base;
    rp8[i + 1] = v;
    if (i + 1 < n8) cur8[i + 1] = v;
  }
  if (i < n1) {
    int blk = i >> 11;
    int base = blk ? bsB[blk - 1] : 0;
    rp[i + 1] += base;
  }
}

// add inclusive block-offsets (no cursor); writes arr[0]=0
__global__ void scan_add(int* __restrict__ arr, const int* __restrict__ bsA, int n)
{
  int i = blockIdx.x * blockDim.x + threadIdx.x;
  if (i == 0) arr[0] = 0;
  if (i < n) {
    int blk = i >> 11;
    int base = blk ? bsA[blk - 1] : 0;
    arr[i + 1] += base;
  }
}

// ===== degree-bucket sort via per-block LDS histograms (NO global atomics) ==
// bin = segid*NDB + min(degree, NDB-1); blocked counts dhb[bin][block]
// (bin-major) -> exclusive scan -> scatter with LDS-computed in-block rank.
// Bin-major order = (segment, degree, block) -> perm is segment-contiguous.
static __device__ __forceinline__ int segid_of(int g) {
  if      (g < NT)          return 0;
  else if (g < NT + NA)     return 1;
  else if (g < NT + 2*NA)   return 2;
  else                      return 3;
}
static __device__ __forceinline__ int segbase_of(int g) {
  if      (g < NT)          return 0;
  else if (g < NT + NA)     return NT;
  else if (g < NT + 2*NA)   return NT + NA;
  else                      return NT + 2*NA;
}

__global__ __launch_bounds__(256) void deg_hist_blk(const int* __restrict__ rp,
    int* __restrict__ dhb)
{
  __shared__ int h[256];
  h[threadIdx.x] = 0;
  __syncthreads();
  int g = blockIdx.x * 256 + threadIdx.x;
  if (g < NTOT) {
    int deg = min(rp[g + 1] - rp[g], NDB - 1);
    atomicAdd(&h[segid_of(g) * NDB + deg], 1);
  }
  __syncthreads();
  dhb[(size_t)threadIdx.x * NBL + blockIdx.x] = h[threadIdx.x];
}

__global__ __launch_bounds__(256) void deg_scat_blk(const int* __restrict__ rp,
    const int* __restrict__ dhbs, int* __restrict__ perm)
{
  __shared__ int h[256];
  h[threadIdx.x] = 0;
  __syncthreads();
  int g = blockIdx.x * 256 + threadIdx.x;
  int bin = 0, rank = 0;
  if (g < NTOT) {
    int deg = min(rp[g + 1] - rp[g], NDB - 1);
    bin = segid_of(g) * NDB + deg;
    rank = atomicAdd(&h[bin], 1);
  }
  if (g < NTOT) {
    int pos = dhbs[(size_t)bin * NBL + blockIdx.x] + rank;
    perm[pos] = g - segbase_of(g);
  }
}

// =============== atomic-free GAT aggregation, node per lane-group ==========
// Nodes assigned via degree-sorted perm so the NPW lane-groups of a wave have
// near-equal trip counts (kills exec-mask divergence). Output bitwise same.
struct AggTask {
  int g0, Nd;
  const float* als; const float* ald;
  const ushort* z;  ushort* out;
};

template<int F>
__global__ __launch_bounds__(256) void agg_multi(const int* __restrict__ rp,
    const int* __restrict__ ssrc, const int* __restrict__ perm,
    AggTask C0A, AggTask C0B, AggTask C1A, AggTask C1B,
    int split0, int split1, int btot)
{
  constexpr int LPN = (F == 128) ? 16 : 8;   // lanes per node
  constexpr int NPW = 64 / LPN;              // nodes per wave
  int b = blockIdx.x;
  int cls = (b >> 2) & 1;                    // XCD class
  int lb = (b >> 3) * 4 + (b & 3);           // linear block index within class
  if (lb >= btot) return;
  AggTask T;
  if (cls == 0) { if (lb < split0) T = C0A; else { T = C0B; lb -= split0; } }
  else          { if (lb < split1) T = C1A; else { T = C1B; lb -= split1; } }
  int wv = threadIdx.x >> 6, lane = threadIdx.x & 63;
  int grp = lane / LPN, lg = lane % LPN;
  int idx = (lb * 4 + wv) * NPW + grp;
  if (idx >= T.Nd) return;
  int n = perm[T.g0 + idx];
  int g = T.g0 + n;
  int start = rp[g], end = rp[g + 1];
  int hh = (F == 128) ? (lg >> 1) : lg;      // head owning this lane's feats
  float ad_h = T.ald[(size_t)n * 8 + hh];

  float den = 0.f;
  float acc[8] = {};
  int e = start;
  for (; e + 1 < end; e += 2) {
    int sn0 = ssrc[e], sn1 = ssrc[e + 1];
    uint4 z0 = *reinterpret_cast<const uint4*>(T.z + (size_t)sn0 * F + lg * 8);
    uint4 z1 = *reinterpret_cast<const uint4*>(T.z + (size_t)sn1 * F + lg * 8);
    float a0 = T.als[(size_t)sn0 * 8 + hh] + ad_h;
    float a1 = T.als[(size_t)sn1 * 8 + hh] + ad_h;
    a0 = a0 > 0.f ? a0 : 0.2f * a0;
    a1 = a1 > 0.f ? a1 : 0.2f * a1;
    float p0 = __expf(fminf(a0, 30.f));
    float p1 = __expf(fminf(a1, 30.f));
    den += p0 + p1;
    acc[0] = fmaf(p0, u2f_lo(z0.x), fmaf(p1, u2f_lo(z1.x), acc[0]));
    acc[1] = fmaf(p0, u2f_hi(z0.x), fmaf(p1, u2f_hi(z1.x), acc[1]));
    acc[2] = fmaf(p0, u2f_lo(z0.y), fmaf(p1, u2f_lo(z1.y), acc[2]));
    acc[3] = fmaf(p0, u2f_hi(z0.y), fmaf(p1, u2f_hi(z1.y), acc[3]));
    acc[4] = fmaf(p0, u2f_lo(z0.z), fmaf(p1, u2f_lo(z1.z), acc[4]));
    acc[5] = fmaf(p0, u2f_hi(z0.z), fmaf(p1, u2f_hi(z1.z), acc[5]));
    acc[6] = fmaf(p0, u2f_lo(z0.w), fmaf(p1, u2f_lo(z1.w), acc[6]));
    acc[7] = fmaf(p0, u2f_hi(z0.w), fmaf(p1, u2f_hi(z1.w), acc[7]));
  }
  if (e < end) {
    int sn = ssrc[e];
    uint4 zv = *reinterpret_cast<const uint4*>(T.z + (size_t)sn * F + lg * 8);
    float a = T.als[(size_t)sn * 8 + hh] + ad_h;
    a = a > 0.f ? a : 0.2f * a;
    float p = __expf(fminf(a, 30.f));
    den += p;
    acc[0] = fmaf(p, u2f_lo(zv.x), acc[0]);
    acc[1] = fmaf(p, u2f_hi(zv.x), acc[1]);
    acc[2] = fmaf(p, u2f_lo(zv.y), acc[2]);
    acc[3] = fmaf(p, u2f_hi(zv.y), acc[3]);
    acc[4] = fmaf(p, u2f_lo(zv.z), acc[4]);
    acc[5] = fmaf(p, u2f_hi(zv.z), acc[5]);
    acc[6] = fmaf(p, u2f_lo(zv.w), acc[6]);
    acc[7] = fmaf(p, u2f_hi(zv.w), acc[7]);
  }
  float inv = 1.f / fmaxf(den, 1e-16f);
  unsigned int pk[4];
#pragma unroll
  for (int k2 = 0; k2 < 4; k2++)
    pk[k2] = (unsigned int)f2b(fmaxf(acc[2*k2] * inv, 0.f))
           | ((unsigned int)f2b(fmaxf(acc[2*k2+1] * inv, 0.f)) << 16);
  *reinterpret_cast<uint4*>(T.out + (size_t)n * F + lg * 8)
      = make_uint4(pk[0], pk[1], pk[2], pk[3]);
}

// ---- semantic softmax (K=2) combine + LayerNorm + ReLU, 2 tasks, F=128 ----
__global__ __launch_bounds__(256) void combine2_k(
    const ushort* __restrict__ o00, const ushort* __restrict__ o01,
    const float* __restrict__ sc0, float invn0, ushort* __restrict__ out0, int N0,
    const ushort* __restrict__ o10, const ushort* __restrict__ o11,
    const float* __restrict__ sc1, float invn1, ushort* __restrict__ out1, int N1,
    const float* __restrict__ g, const float* __restrict__ bb)
{
  int c1 = (N0 + 3) / 4;
  int b = blockIdx.x;
  const ushort *o0, *o1; const float* sc; float invn; ushort* outp; int N, lb;
  if (b < c1) { o0=o00; o1=o01; sc=sc0; invn=invn0; outp=out0; N=N0; lb=b; }
  else        { o0=o10; o1=o11; sc=sc1; invn=invn1; outp=out1; N=N1; lb=b-c1; }
  int wv = threadIdx.x >> 6, lane = threadIdx.x & 63;
  int n = lb * 4 + wv;
  if (n >= N) return;
  float s0 = sc[0] * invn, s1 = sc[1] * invn;
  float mx = fmaxf(s0, s1);
  float e0 = __expf(s0 - mx), e1 = __expf(s1 - mx);
  float w0 = e0 / (e0 + e1), w1 = e1 / (e0 + e1);
  float x[2];
#pragma unroll
  for (int jj = 0; jj < 2; jj++) {
    int idx = lane + 64 * jj;
    x[jj] = w0 * b2f(o0[(size_t)n * 128 + idx]) + w1 * b2f(o1[(size_t)n * 128 + idx]);
  }
  float sum = x[0] + x[1];
#pragma unroll
  for (int o = 32; o > 0; o >>= 1) sum += __shfl_xor(sum, o);
  float mu = sum / 128.f;
  float vs = 0.f;
#pragma unroll
  for (int jj = 0; jj < 2; jj++) { float dd = x[jj] - mu; vs = fmaf(dd, dd, vs); }
#pragma unroll
  for (int o = 32; o > 0; o >>= 1) vs += __shfl_xor(vs, o);
  float rstd = rsqrtf(vs / 128.f + 1e-5f);
#pragma unroll
  for (int jj = 0; jj < 2; jj++) {
    int idx = lane + 64 * jj;
    float y = (x[jj] - mu) * rstd * g[idx] + bb[idx];
    outp[(size_t)n * 128 + idx] = f2b(fmaxf(y, 0.f));
  }
}

// ---- layer-2 combine + LN + ReLU + final linear [64]->[2], F=64 ----------
__global__ __launch_bounds__(256) void combine_final_k(
    const ushort* __restrict__ o0, const ushort* __restrict__ o1,
    const float* __restrict__ sc, float invn,
    const float* __restrict__ g, const float* __restrict__ bb,
    const float* __restrict__ lw, const float* __restrict__ lb,
    float* __restrict__ outp, int N)
{
  int wv = threadIdx.x >> 6, lane = threadIdx.x & 63;
  int n = blockIdx.x * 4 + wv;
  if (n >= N) return;
  float s0 = sc[0] * invn, s1 = sc[1] * invn;
  float mx = fmaxf(s0, s1);
  float e0 = __expf(s0 - mx), e1 = __expf(s1 - mx);
  float w0 = e0 / (e0 + e1), w1 = e1 / (e0 + e1);
  float x = w0 * b2f(o0[(size_t)n * 64 + lane]) + w1 * b2f(o1[(size_t)n * 64 + lane]);
  float sum = x;
#pragma unroll
  for (int o = 32; o > 0; o >>= 1) sum += __shfl_xor(sum, o);
  float mu = sum / 64.f;
  float dd = x - mu;
  float vs = dd * dd;
#pragma unroll
  for (int o = 32; o > 0; o >>= 1) vs += __shfl_xor(vs, o);
  float rstd = rsqrtf(vs / 64.f + 1e-5f);
  float y = fmaxf((x - mu) * rstd * g[lane] + bb[lane], 0.f);
  float p0 = y * lw[lane * 2 + 0];
  float p1 = y * lw[lane * 2 + 1];
#pragma unroll
  for (int o = 32; o > 0; o >>= 1) { p0 += __shfl_xor(p0, o); p1 += __shfl_xor(p1, o); }
  if (lane == 0) {
    outp[(size_t)n * 2 + 0] = p0 + lb[0];
    outp[(size_t)n * 2 + 1] = p1 + lb[1];
  }
}

extern "C" void kernel_launch(void* const* d_in, const int* in_sizes, int n_in,
                              void* d_out, int out_size, void* d_ws, size_t ws_size,
                              hipStream_t stream)
{
  (void)in_sizes; (void)n_in; (void)out_size;
  const float* x_a = (const float*)d_in[0];
  const float* x_t = (const float*)d_in[1];
  const int* eat_s = (const int*)d_in[2];
  const int* eat_d = (const int*)d_in[3];
  const int* eta_s = (const int*)d_in[4];
  const int* eta_d = (const int*)d_in[5];
  const int* eaa_s = (const int*)d_in[6];
  const int* eaa_d = (const int*)d_in[7];
  const int* ett_s = (const int*)d_in[8];
  const int* ett_d = (const int*)d_in[9];
  const float* W_a1 = (const float*)d_in[10]; const float* b_a1 = (const float*)d_in[11];
  const float* W_t1 = (const float*)d_in[12]; const float* b_t1 = (const float*)d_in[13];
  const float* as_at1 = (const float*)d_in[14]; const float* ad_at1 = (const float*)d_in[15];
  const float* as_ta1 = (const float*)d_in[16]; const float* ad_ta1 = (const float*)d_in[17];
  const float* as_aa1 = (const float*)d_in[18]; const float* ad_aa1 = (const float*)d_in[19];
  const float* as_tt1 = (const float*)d_in[20]; const float* ad_tt1 = (const float*)d_in[21];
  const float* k1_W = (const float*)d_in[22]; const float* k1_b = (const float*)d_in[23];
  const float* q1   = (const float*)d_in[24];
  const float* W_a2 = (const float*)d_in[25]; const float* b_a2 = (const float*)d_in[26];
  const float* W_t2 = (const float*)d_in[27]; const float* b_t2 = (const float*)d_in[28];
  const float* as_ta2 = (const float*)d_in[31]; const float* ad_ta2 = (const float*)d_in[32];
  const float* as_aa2 = (const float*)d_in[33]; const float* ad_aa2 = (const float*)d_in[34];
  const float* k2_W = (const float*)d_in[37]; const float* k2_b = (const float*)d_in[38];
  const float* q2   = (const float*)d_in[39];
  const float* ln1_g = (const float*)d_in[40]; const float* ln1_b = (const float*)d_in[41];
  const float* ln2_g = (const float*)d_in[42]; const float* ln2_b = (const float*)d_in[43];
  const float* lin_W = (const float*)d_in[44]; const float* lin_b = (const float*)d_in[45];

  char* ws = (char*)d_ws;
  size_t off = 0;
  auto alloc = [&](size_t bytes) {
    size_t o = off; off += (bytes + 255) & ~(size_t)255; return o;
  };
  size_t ZA1 = alloc((size_t)NA * HID * 2);     // bf16 z_a; layer2 za2 aliases
  size_t ZT1 = alloc((size_t)NT * HID * 2);     // bf16 z_t; layer2 zt2 aliases
  size_t OTA = alloc((size_t)NA * HID * 2);     // bf16 o_ta -> xa1 in-place
  size_t OAA = alloc((size_t)NA * HID * 2);     // bf16 o_aa; L2: ota2|oaa2 alias
  size_t OAT = alloc((size_t)NT * HID * 2);     // bf16 o_at -> xt1 in-place
  size_t OTT = alloc((size_t)NT * HID * 2);
  size_t A_AS_AT = alloc((size_t)NA * 8 * 4);
  size_t A_AD_TA = alloc((size_t)NA * 8 * 4);
  size_t A_AS_AA = alloc((size_t)NA * 8 * 4);
  size_t A_AD_AA = alloc((size_t)NA * 8 * 4);
  size_t A_T_D_AT = alloc((size_t)NT * 8 * 4);
  size_t A_T_S_TA = alloc((size_t)NT * 8 * 4);
  size_t A_T_S_TT = alloc((size_t)NT * 8 * 4);
  size_t A_T_D_TT = alloc((size_t)NT * 8 * 4);
  // sharded CSR build + compacted final CSR
  size_t RP8  = alloc(((size_t)NSH * NTOT + 1) * 4);
  size_t CUR8 = alloc((size_t)NSH * NTOT * 4);  // doubles as sharded hist
  size_t SSH  = alloc((size_t)ETOT * 4);
  size_t RP   = alloc((size_t)(NTOT + 1) * 4);
  size_t SS   = alloc((size_t)ETOT * 4);
  size_t BSM  = alloc(2048 * 4);
  size_t BSM2 = alloc(256 * 4);
  size_t BSM3 = alloc(256 * 4);
  size_t DHB  = alloc((size_t)NDEG * 4);        // blocked degree hist
  size_t DHBS = alloc(((size_t)NDEG + 1) * 4);  // its exclusive scan
  size_t PERM = alloc((size_t)NTOT * 4);        // degree-sorted node perm
  size_t SC   = alloc(256);                     // 6 score accumulators
  if (off > ws_size) return;                    // fail visibly

  ushort* za1 = (ushort*)(ws + ZA1);
  ushort* zt1 = (ushort*)(ws + ZT1);
  ushort* ota = (ushort*)(ws + OTA);
  ushort* oaa = (ushort*)(ws + OAA);
  ushort* oat = (ushort*)(ws + OAT);
  ushort* ott = (ushort*)(ws + OTT);
  float* aASAT = (float*)(ws + A_AS_AT);
  float* aADTA = (float*)(ws + A_AD_TA);
  float* aASAA = (float*)(ws + A_AS_AA);
  float* aADAA = (float*)(ws + A_AD_AA);
  float* aTDAT = (float*)(ws + A_T_D_AT);
  float* aTSTA = (float*)(ws + A_T_S_TA);
  float* aTSTT = (float*)(ws + A_T_S_TT);
  float* aTDTT = (float*)(ws + A_T_D_TT);
  int* rp8  = (int*)(ws + RP8);
  int* cur8 = (int*)(ws + CUR8);
  int* ssh  = (int*)(ws + SSH);
  int* rp   = (int*)(ws + RP);
  int* ssrc = (int*)(ws + SS);
  int* bsum = (int*)(ws + BSM);
  int* bsum2= (int*)(ws + BSM2);
  int* bsum3= (int*)(ws + BSM3);
  int* dhb  = (int*)(ws + DHB);
  int* dhbs = (int*)(ws + DHBS);
  int* perm = (int*)(ws + PERM);
  float* scp = (float*)(ws + SC);
  // layer-2 aliases
  ushort* za2 = za1;                                   // [NA,64] bf16
  ushort* zt2 = zt1;                                   // [NT,64] bf16
  ushort* ota2 = oaa;                                  // [NA,64] bf16
  ushort* oaa2 = (ushort*)(ws + OAA + (size_t)NA * OUTF * 2);  // [NA,64] bf16

  const int TA = (NA + 63) / 64, TT = (NT + 63) / 64;  // row tiles
  const int EBL = (ETOT + 255) / 256;
  const int SCN8 = NSH * NTOT;
  const int SBL8 = (SCN8 + 2047) / 2048;
  const int SBL1 = (NTOT + 2047) / 2048;
  const int SBLD = (NDEG + 2047) / 2048;

  // ---- sharded CSR build + compact + contention-free degree sort ----
  hipMemsetAsync(cur8, 0, (size_t)SCN8 * 4, stream);
  hist4_sh<<<EBL, 256, 0, stream>>>(eat_d, eta_d, eaa_d, ett_d, cur8, scp);
  scan_blk<<<SBL8, 256, 0, stream>>>(cur8, rp8 + 1, bsum, SCN8);
  scan_blk_sum8<<<SBL1, 256, 0, stream>>>(cur8, rp + 1, bsum2, NTOT);
  scan_two<<<2, 256, 0, stream>>>(bsum, SBL8, bsum2, SBL1);
  scan_addM<<<(SCN8 + 255) / 256, 256, 0, stream>>>(rp8, cur8, bsum, SCN8,
                                                    rp, bsum2, NTOT);
  scatter_sh<<<EBL, 256, 0, stream>>>(eat_s, eat_d, eta_s, eta_d,
                                      eaa_s, eaa_d, ett_s, ett_d, cur8, ssh);
  compact_k<<<NBL, 256, 0, stream>>>(rp8, rp, ssh, ssrc);
  deg_hist_blk<<<NBL, 256, 0, stream>>>(rp, dhb);
  scan_blk<<<SBLD, 256, 0, stream>>>(dhb, dhbs + 1, bsum3, NDEG);
  scan_two<<<2, 256, 0, stream>>>(bsum3, SBLD, bsum3, 0);
  scan_add<<<(NDEG + 255) / 256, 256, 0, stream>>>(dhbs, bsum3, NDEG);
  deg_scat_blk<<<NBL, 256, 0, stream>>>(rp, dhbs, perm);

  // ============ Layer 1 ============
  zgemm_k<4,16,FA,HID,2,float><<<(TA+1)/2,256,0,stream>>>(x_a, W_a1, b_a1,
      as_at1, ad_ta1, as_aa1, ad_aa1, aASAT, aADTA, aASAA, aADAA, za1, NA);
  zgemm_k<4,16,FT,HID,4,float><<<(TT+3)/4,256,0,stream>>>(x_t, W_t1, b_t1,
      ad_at1, as_ta1, as_tt1, ad_tt1, aTDAT, aTSTA, aTSTT, aTDTT, zt1, NT);
  {
    const int BT = (NT + 15) / 16, BA = (NA + 15) / 16;
    const int btot = BT + BA;
    const int grid = ((btot + 3) / 4) * 8;
    AggTask Tat{0,        NT, aASAT, aTDAT, za1, oat};
    AggTask Taa{NT+NA,    NA, aASAA, aADAA, za1, oaa};
    AggTask Tta{NT,       NA, aTSTA, aADTA, zt1, ota};
    AggTask Ttt{NT+2*NA,  NT, aTSTT, aTDTT, zt1, ott};
    agg_multi<128><<<grid, 256, 0, stream>>>(rp, ssrc, perm,
        Tat, Taa, Tta, Ttt, BT, BA, btot);
  }
  {
    const int bA = (TA + 3) / 4, bT = (TT + 3) / 4;
    score_k<HID,HID,4><<<2*bA + 2*bT, 256, 0, stream>>>(ota, oaa, oat, ott,
        k1_W, k1_b, q1, scp,
        make_int4(bA, 2*bA, 2*bA + bT, 2*bA + 2*bT),
        make_int4(NA, NA, NT, NT));
  }
  combine2_k<<<(NA/4) + (NT/4), 256, 0, stream>>>(
      ota, oaa, scp + 0, 1.f/NA, ota, NA,
      oat, ott, scp + 2, 1.f/NT, oat, NT, ln1_g, ln1_b);

  // ============ Layer 2 (only the address path feeds the output) ============
  zgemm_k<3,8,HID,OUTF,2,ushort><<<(TA+1)/2,256,0,stream>>>(ota, W_a2, b_a2,
      ad_ta2, as_aa2, ad_aa2, nullptr, aADTA, aASAA, aADAA, nullptr, za2, NA);
  zgemm_k<1,8,HID,OUTF,4,ushort><<<(TT+3)/4,256,0,stream>>>(oat, W_t2, b_t2,
      as_ta2, nullptr, nullptr, nullptr, aTSTA, nullptr, nullptr, nullptr, zt2, NT);
  {
    const int BA2 = (NA + 31) / 32;
    const int grid = ((BA2 + 3) / 4) * 8;
    AggTask Taa2{NT+NA, NA, aASAA, aADAA, za2, oaa2};
    AggTask Tta2{NT,    NA, aTSTA, aADTA, zt2, ota2};
    agg_multi<64><<<grid, 256, 0, stream>>>(rp, ssrc, perm,
        Taa2, Taa2, Tta2, Tta2, BA2, BA2, BA2);
  }
  {
    const int bA = (TA + 3) / 4;
    score_k<OUTF,OUTF,4><<<2*bA, 256, 0, stream>>>(ota2, oaa2, ota2, ota2,
        k2_W, k2_b, q2, scp + 4,
        make_int4(bA, 2*bA, 2*bA, 2*bA),
        make_int4(NA, NA, NA, NA));
  }
  combine_final_k<<<NA/4, 256, 0, stream>>>(ota2, oaa2, scp + 4, 1.f/NA,
      ln2_g, ln2_b, lin_W, lin_b, (float*)d_out, NA);
}

// Round 13
// 517.828 us; speedup vs baseline: 3.3316x; 1.0493x over previous
//
#include <hip/hip_runtime.h>
#include <cstdint>
#include <cstddef>
#include <type_traits>

#define NA 50000
#define NT 100000
#define FA 128
#define FT 64
#define HID 128
#define OUTF 64
#define HEADS 8
#define E1 500000
#define E2 250000
#define NTOT (2*NT + 2*NA)          // concatenated dst-node space [at|ta|aa|tt]
#define ETOT (2*E1 + 2*E2)          // concatenated edge space
#define NSH 8                       // CSR build shards (== XCDs heuristic)

typedef __attribute__((ext_vector_type(8))) short short8;
typedef __attribute__((ext_vector_type(4))) float f32x4;

static __device__ __forceinline__ ushort f2b(float f) {  // f32 -> bf16 RNE
  unsigned int u = __float_as_uint(f);
  return (ushort)((u + 0x7fffu + ((u >> 16) & 1u)) >> 16);
}
static __device__ __forceinline__ float b2f(ushort b) {
  return __uint_as_float(((unsigned int)b) << 16);
}
static __device__ __forceinline__ float u2f_lo(unsigned int u) {
  return __uint_as_float(u << 16);
}
static __device__ __forceinline__ float u2f_hi(unsigned int u) {
  return __uint_as_float(u & 0xffff0000u);
}

// ============== shared GEMM building blocks (XOR-swizzled LDS) =============
template<int KK>
static __device__ __forceinline__ int lidx(int row, int off) {
  return row * KK + (off ^ ((row & 7) << 3));
}

template<int KK, int M>
static __device__ __forceinline__ void stageB(const float* __restrict__ W,
                                              ushort* __restrict__ Bls)
{
  constexpr int TPC = 256 / M;          // threads per col
  constexpr int CH  = KK / TPC;         // k-chunk per thread
  constexpr int BL  = (CH < 16) ? CH : 16;
  int t = threadIdx.x;
  int col = t % M;
  int k0 = (t / M) * CH;
  const float* Wp = W + col;
#pragma unroll
  for (int b = 0; b < CH; b += BL) {
    float v[BL];
#pragma unroll
    for (int i = 0; i < BL; i++) v[i] = Wp[(size_t)(k0 + b + i) * M];
#pragma unroll
    for (int q = 0; q < BL / 8; q++) {
      union { ushort u[8]; uint4 x; } p;
#pragma unroll
      for (int i = 0; i < 8; i++) p.u[i] = f2b(v[q * 8 + i]);
      *reinterpret_cast<uint4*>(&Bls[lidx<KK>(col, k0 + b + q * 8)]) = p.x;
    }
  }
}

template<int KK, typename AT>
struct ARegs {
  float4 f[std::is_same<AT, float>::value ? KK / 16 : 1];
  uint4  u[std::is_same<AT, float>::value ? 1 : KK / 32];
};

template<int KK, typename AT>
static __device__ __forceinline__ void loadA(const AT* __restrict__ A, int N,
                                             int row0, ARegs<KK, AT>& R)
{
  int t = threadIdx.x;
  int arow = t >> 2, ac0 = (t & 3) * (KK / 4);
  int row = row0 + arow;
  bool ok = row < N;
  const AT* Ap = A + (size_t)row * KK + ac0;
  if constexpr (std::is_same<AT, float>::value) {
#pragma unroll
    for (int j = 0; j < KK / 16; j++)
      R.f[j] = ok ? *reinterpret_cast<const float4*>(Ap + j * 4)
                  : make_float4(0.f, 0.f, 0.f, 0.f);
  } else {
#pragma unroll
    for (int j = 0; j < KK / 32; j++)
      R.u[j] = ok ? *reinterpret_cast<const uint4*>(Ap + j * 8)
                  : make_uint4(0, 0, 0, 0);
  }
}

template<int KK, typename AT>
static __device__ __forceinline__ void writeA(const ARegs<KK, AT>& R,
                                              ushort* __restrict__ Als)
{
  int t = threadIdx.x;
  int arow = t >> 2, ac0 = (t & 3) * (KK / 4);
#pragma unroll
  for (int j = 0; j < KK / 32; j++) {
    uint4 w;
    if constexpr (std::is_same<AT, float>::value) {
      union { ushort u[8]; uint4 x; } p;
      float4 a0 = R.f[2 * j], a1 = R.f[2 * j + 1];
      p.u[0] = f2b(a0.x); p.u[1] = f2b(a0.y); p.u[2] = f2b(a0.z); p.u[3] = f2b(a0.w);
      p.u[4] = f2b(a1.x); p.u[5] = f2b(a1.y); p.u[6] = f2b(a1.z); p.u[7] = f2b(a1.w);
      w = p.x;
    } else {
      w = R.u[j];
    }
    *reinterpret_cast<uint4*>(&Als[lidx<KK>(arow, ac0 + j * 8)]) = w;
  }
}

template<int KK, int NCT>
static __device__ __forceinline__ void mfma_tile(const ushort* __restrict__ Als,
    const ushort* __restrict__ Bls, f32x4* acc)
{
  int lane = threadIdx.x & 63, w = threadIdx.x >> 6;
  int l15 = lane & 15, l4 = lane >> 4;
#pragma unroll
  for (int ks = 0; ks < KK / 32; ks++) {
    short8 af = *reinterpret_cast<const short8*>(
        &Als[lidx<KK>(16 * w + l15, ks * 32 + l4 * 8)]);
#pragma unroll
    for (int n = 0; n < NCT; n++) {
      short8 bf = *reinterpret_cast<const short8*>(
          &Bls[lidx<KK>(16 * n + l15, ks * 32 + l4 * 8)]);
      acc[n] = __builtin_amdgcn_mfma_f32_16x16x32_bf16(af, bf, acc[n], 0, 0, 0);
    }
  }
}

// ====== z-projection GEMM (full M per block, TPB row-tiles, W staged once) =
template<int NV, int DD, int KK, int M, int TPB, typename AT>
__global__ __launch_bounds__(256) void zgemm_k(
    const AT* __restrict__ A, const float* __restrict__ W,
    const float* __restrict__ bias,
    const float* __restrict__ v0, const float* __restrict__ v1,
    const float* __restrict__ v2, const float* __restrict__ v3,
    float* __restrict__ o0, float* __restrict__ o1,
    float* __restrict__ o2, float* __restrict__ o3,
    ushort* __restrict__ Cb, int N)
{
  constexpr int NCT = M / 16;
  __shared__ __align__(16) ushort Bls[M * KK];
  __shared__ __align__(16) ushort Als[64 * KK];
  int t = threadIdx.x, w = t >> 6, lane = t & 63;
  int l15 = lane & 15, l4 = lane >> 4;
  int ntiles = (N + 63) >> 6;
  int tile0 = blockIdx.x * TPB;
  int nt = min(TPB, ntiles - tile0);

  stageB<KK, M>(W, Bls);
  ARegs<KK, AT> R;
  loadA<KK, AT>(A, N, tile0 * 64, R);

  float bv[NCT], aw0[NCT], aw1[NCT], aw2[NCT], aw3[NCT];
#pragma unroll
  for (int n = 0; n < NCT; n++) {
    int col = 16 * n + l15;
    bv[n] = bias[col];
    int head = (DD == 16) ? n : (n * 2 + (l15 >> 3));
    int vi = head * DD + (l15 & (DD - 1));
    aw0[n] = v0[vi];
    aw1[n] = (NV > 1) ? v1[vi] : 0.f;
    aw2[n] = (NV > 2) ? v2[vi] : 0.f;
    aw3[n] = (NV > 3) ? v3[vi] : 0.f;
  }

  for (int i = 0; i < nt; i++) {
    int row0 = (tile0 + i) * 64;
    __syncthreads();
    writeA<KK, AT>(R, Als);
    __syncthreads();
    if (i + 1 < nt) loadA<KK, AT>(A, N, row0 + 64, R);
    f32x4 acc[NCT];
#pragma unroll
    for (int n = 0; n < NCT; n++) acc[n] = (f32x4){0.f, 0.f, 0.f, 0.f};
    mfma_tile<KK, NCT>(Als, Bls, acc);

#pragma unroll
    for (int n = 0; n < NCT; n++) {
      int col = 16 * n + l15;
      int head = (DD == 16) ? n : (n * 2 + (l15 >> 3));
#pragma unroll
      for (int r = 0; r < 4; r++) {
        int row = row0 + 16 * w + l4 * 4 + r;
        float v = acc[n][r] + bv[n];
        if (row < N) Cb[(size_t)row * M + col] = f2b(v);
        float a0 = v * aw0[n], a1 = v * aw1[n], a2 = v * aw2[n], a3 = v * aw3[n];
#pragma unroll
        for (int o = 1; o < DD; o <<= 1) {
          a0 += __shfl_xor(a0, o);
          if (NV > 1) a1 += __shfl_xor(a1, o);
          if (NV > 2) a2 += __shfl_xor(a2, o);
          if (NV > 3) a3 += __shfl_xor(a3, o);
        }
        if ((l15 & (DD - 1)) == 0 && row < N) {
          o0[(size_t)row * 8 + head] = a0;
          if (NV > 1) o1[(size_t)row * 8 + head] = a1;
          if (NV > 2) o2[(size_t)row * 8 + head] = a2;
          if (NV > 3) o3[(size_t)row * 8 + head] = a3;
        }
      }
    }
  }
}

// ====== multi-task score GEMM: atomicAdd(scp[t], sum tanh(C+b)*q) ==========
template<int KK, int M, int TPB>
__global__ __launch_bounds__(256) void score_k(
    const ushort* __restrict__ A0, const ushort* __restrict__ A1,
    const ushort* __restrict__ A2, const ushort* __restrict__ A3,
    const float* __restrict__ W, const float* __restrict__ bias,
    const float* __restrict__ qv, float* __restrict__ scp,
    int4 cumB, int4 Ns)
{
  constexpr int NCT = M / 16;
  __shared__ __align__(16) ushort Bls[M * KK];
  __shared__ __align__(16) ushort Als[64 * KK];
  __shared__ float red[4];
  int b = blockIdx.x;
  int tsk, bbase, N; const ushort* A;
  if      (b < cumB.x) { tsk = 0; bbase = 0;      N = Ns.x; A = A0; }
  else if (b < cumB.y) { tsk = 1; bbase = cumB.x; N = Ns.y; A = A1; }
  else if (b < cumB.z) { tsk = 2; bbase = cumB.y; N = Ns.z; A = A2; }
  else                 { tsk = 3; bbase = cumB.z; N = Ns.w; A = A3; }
  int t = threadIdx.x, w = t >> 6, lane = t & 63;
  int l15 = lane & 15, l4 = lane >> 4;
  int ntiles = (N + 63) >> 6;
  int tile0 = (b - bbase) * TPB;
  int nt = min(TPB, ntiles - tile0);

  stageB<KK, M>(W, Bls);
  ARegs<KK, ushort> R;
  loadA<KK, ushort>(A, N, tile0 * 64, R);

  float bb[NCT], qb[NCT];
#pragma unroll
  for (int n = 0; n < NCT; n++) {
    int col = 16 * n + l15;
    bb[n] = bias[col]; qb[n] = qv[col];
  }

  float ls = 0.f;
  for (int i = 0; i < nt; i++) {
    int row0 = (tile0 + i) * 64;
    __syncthreads();
    writeA<KK, ushort>(R, Als);
    __syncthreads();
    if (i + 1 < nt) loadA<KK, ushort>(A, N, row0 + 64, R);
    f32x4 acc[NCT];
#pragma unroll
    for (int n = 0; n < NCT; n++) acc[n] = (f32x4){0.f, 0.f, 0.f, 0.f};
    mfma_tile<KK, NCT>(Als, Bls, acc);
#pragma unroll
    for (int n = 0; n < NCT; n++) {
#pragma unroll
      for (int r = 0; r < 4; r++) {
        int row = row0 + 16 * w + l4 * 4 + r;
        if (row < N) ls += tanhf(acc[n][r] + bb[n]) * qb[n];
      }
    }
  }
#pragma unroll
  for (int o = 32; o > 0; o >>= 1) ls += __shfl_xor(ls, o);
  if (lane == 0) red[w] = ls;
  __syncthreads();
  if (t == 0) atomicAdd(&scp[tsk], red[0] + red[1] + red[2] + red[3]);
}

// ============== XCD-sharded CSR build + compaction =========================
__global__ void hist4_sh(const int* __restrict__ d0, const int* __restrict__ d1,
    const int* __restrict__ d2, const int* __restrict__ d3,
    int* __restrict__ cnt8, float* __restrict__ scp)
{
  if (blockIdx.x == 0 && threadIdx.x < 8) scp[threadIdx.x] = 0.f;
  int e = blockIdx.x * 256 + threadIdx.x;
  int sh = blockIdx.x & (NSH - 1);
  int d;
  if      (e < E1)          d = d0[e];
  else if (e < 2*E1)        d = d1[e - E1] + NT;
  else if (e < 2*E1 + E2)   d = d2[e - 2*E1] + NT + NA;
  else if (e < ETOT)        d = d3[e - 2*E1 - E2] + NT + 2*NA;
  else return;
  atomicAdd(&cnt8[sh * NTOT + d], 1);
}

__global__ void scatter_sh(const int* __restrict__ s0, const int* __restrict__ d0,
    const int* __restrict__ s1, const int* __restrict__ d1,
    const int* __restrict__ s2, const int* __restrict__ d2,
    const int* __restrict__ s3, const int* __restrict__ d3,
    int* __restrict__ cur8, int* __restrict__ ssh)
{
  int e = blockIdx.x * 256 + threadIdx.x;
  int sh = blockIdx.x & (NSH - 1);
  int d, s;
  if      (e < E1)          { d = d0[e];                           s = s0[e]; }
  else if (e < 2*E1)        { d = d1[e - E1] + NT;                 s = s1[e - E1]; }
  else if (e < 2*E1 + E2)   { d = d2[e - 2*E1] + NT + NA;          s = s2[e - 2*E1]; }
  else if (e < ETOT)        { d = d3[e - 2*E1 - E2] + NT + 2*NA;   s = s3[e - 2*E1 - E2]; }
  else return;
  int p = atomicAdd(&cur8[sh * NTOT + d], 1);
  ssh[p] = s;
}

// merge each node's 8 shard-segments into the contiguous final CSR order
__global__ void compact_k(const int* __restrict__ rp8, const int* __restrict__ rp,
    const int* __restrict__ ssh, int* __restrict__ ssrc)
{
  int g = blockIdx.x * 256 + threadIdx.x;
  if (g >= NTOT) return;
  int w = rp[g];
#pragma unroll
  for (int s = 0; s < NSH; s++) {
    int b0 = rp8[s * NTOT + g], b1 = rp8[s * NTOT + g + 1];
    for (int e = b0; e < b1; e++) ssrc[w++] = ssh[e];
  }
}

// per-block inclusive scan (256 thr x 8) of in -> rp1 (=rp+1); totals -> bsum
__global__ __launch_bounds__(256) void scan_blk(const int* __restrict__ in,
    int* __restrict__ rp1, int* __restrict__ bsum, int n)
{
  __shared__ int sh[256];
  int base = blockIdx.x * 2048;
  int t = threadIdx.x;
  int v[8]; int s = 0;
#pragma unroll
  for (int k = 0; k < 8; k++) {
    int i = base + t * 8 + k;
    v[k] = (i < n) ? in[i] : 0; s += v[k];
  }
  sh[t] = s; __syncthreads();
  for (int o = 1; o < 256; o <<= 1) {
    int x = (t >= o) ? sh[t - o] : 0;
    __syncthreads(); sh[t] += x; __syncthreads();
  }
  int run = (t == 0) ? 0 : sh[t - 1];
  if (t == 255 && bsum) bsum[blockIdx.x] = sh[255];
#pragma unroll
  for (int k = 0; k < 8; k++) {
    int i = base + t * 8 + k;
    run += v[k];
    if (i < n) rp1[i] = run;
  }
}

// like scan_blk, but element i = sum over 8 shards of cnt8[s*NTOT+i]
__global__ __launch_bounds__(256) void scan_blk_sum8(const int* __restrict__ cnt8,
    int* __restrict__ rp1, int* __restrict__ bsum, int n)
{
  __shared__ int sh[256];
  int base = blockIdx.x * 2048;
  int t = threadIdx.x;
  int v[8]; int s = 0;
#pragma unroll
  for (int k = 0; k < 8; k++) {
    int i = base + t * 8 + k;
    int x = 0;
    if (i < n) {
#pragma unroll
      for (int sh2 = 0; sh2 < NSH; sh2++) x += cnt8[sh2 * NTOT + i];
    }
    v[k] = x; s += x;
  }
  sh[t] = s; __syncthreads();
  for (int o = 1; o < 256; o <<= 1) {
    int x = (t >= o) ? sh[t - o] : 0;
    __syncthreads(); sh[t] += x; __syncthreads();
  }
  int run = (t == 0) ? 0 : sh[t - 1];
  if (t == 255 && bsum) bsum[blockIdx.x] = sh[255];
#pragma unroll
  for (int k = 0; k < 8; k++) {
    int i = base + t * 8 + k;
    run += v[k];
    if (i < n) rp1[i] = run;
  }
}

// up to two independent in-place single-block scans in one dispatch
__global__ __launch_bounds__(256) void scan_two(int* __restrict__ b0, int n0,
                                                int* __restrict__ b1, int n1)
{
  __shared__ int sh[256];
  int* arr = blockIdx.x ? b1 : b0;
  int n = blockIdx.x ? n1 : n0;
  if (n <= 0) return;
  int t = threadIdx.x;
  int v[8]; int s = 0;
#pragma unroll
  for (int k = 0; k < 8; k++) {
    int i = t * 8 + k;
    v[k] = (i < n) ? arr[i] : 0; s += v[k];
  }
  sh[t] = s; __syncthreads();
  for (int o = 1; o < 256; o <<= 1) {
    int x = (t >= o) ? sh[t - o] : 0;
    __syncthreads(); sh[t] += x; __syncthreads();
  }
  int run = (t == 0) ? 0 : sh[t - 1];
#pragma unroll
  for (int k = 0; k < 8; k++) {
    int i = t * 8 + k;
    run += v[k];
    if (i < n) arr[i] = run;
  }
}

// merged: add block-offsets for rp8/cur8 (n8 elems) AND rp (n1 elems)
__global__ void scan_addM(int* __restrict__ rp8, int* __restrict__ cur8,
    const int* __restrict__ bsA, int n8,
    int* __restrict__ rp, const int* __restrict__ bsB, int n1)
{
  int i = blockIdx.x * blockDim.x + threadIdx.x;
  if (i == 0) { rp8[0] = 0; cur8[0] = 0; rp[0] = 0; }
  if (i < n8) {
    int blk = i >> 11;
    int base = blk ? bsA[blk - 1] : 0;
    int v = rp8[i + 1] + base;
    rp8[i + 1] = v;
    if (i + 1 < n8) cur8[i + 1] = v;
  }
  if (i < n1) {
    int blk = i >> 11;
    int base = blk ? bsB[blk - 1] : 0;
    rp[i + 1] += base;
  }
}

// =============== atomic-free GAT aggregation, node per lane-group ==========
// F=128: 16 lanes/node (4 nodes/wave); F=64: 8 lanes/node (8 nodes/wave).
// Lane-private softmax state; single-pass exp (alphas O(1), clamp 30);
// unroll-2 gather chains; XCD-class task split; ReLU + bf16 store.
struct AggTask {
  int g0, Nd;
  const float* als; const float* ald;
  const ushort* z;  ushort* out;
};

template<int F>
__global__ __launch_bounds__(256) void agg_multi(const int* __restrict__ rp,
    const int* __restrict__ ssrc, AggTask C0A, AggTask C0B,
    AggTask C1A, AggTask C1B, int split0, int split1, int btot)
{
  constexpr int LPN = (F == 128) ? 16 : 8;   // lanes per node
  constexpr int NPW = 64 / LPN;              // nodes per wave
  int b = blockIdx.x;
  int cls = (b >> 2) & 1;                    // XCD class
  int lb = (b >> 3) * 4 + (b & 3);           // linear block index within class
  if (lb >= btot) return;
  AggTask T;
  if (cls == 0) { if (lb < split0) T = C0A; else { T = C0B; lb -= split0; } }
  else          { if (lb < split1) T = C1A; else { T = C1B; lb -= split1; } }
  int wv = threadIdx.x >> 6, lane = threadIdx.x & 63;
  int grp = lane / LPN, lg = lane % LPN;
  int n = (lb * 4 + wv) * NPW + grp;
  if (n >= T.Nd) return;
  int g = T.g0 + n;
  int start = rp[g], end = rp[g + 1];
  int hh = (F == 128) ? (lg >> 1) : lg;      // head owning this lane's feats
  float ad_h = T.ald[(size_t)n * 8 + hh];

  float den = 0.f;
  float acc[8] = {};
  int e = start;
  for (; e + 1 < end; e += 2) {
    int sn0 = ssrc[e], sn1 = ssrc[e + 1];
    uint4 z0 = *reinterpret_cast<const uint4*>(T.z + (size_t)sn0 * F + lg * 8);
    uint4 z1 = *reinterpret_cast<const uint4*>(T.z + (size_t)sn1 * F + lg * 8);
    float a0 = T.als[(size_t)sn0 * 8 + hh] + ad_h;
    float a1 = T.als[(size_t)sn1 * 8 + hh] + ad_h;
    a0 = a0 > 0.f ? a0 : 0.2f * a0;
    a1 = a1 > 0.f ? a1 : 0.2f * a1;
    float p0 = __expf(fminf(a0, 30.f));
    float p1 = __expf(fminf(a1, 30.f));
    den += p0 + p1;
    acc[0] = fmaf(p0, u2f_lo(z0.x), fmaf(p1, u2f_lo(z1.x), acc[0]));
    acc[1] = fmaf(p0, u2f_hi(z0.x), fmaf(p1, u2f_hi(z1.x), acc[1]));
    acc[2] = fmaf(p0, u2f_lo(z0.y), fmaf(p1, u2f_lo(z1.y), acc[2]));
    acc[3] = fmaf(p0, u2f_hi(z0.y), fmaf(p1, u2f_hi(z1.y), acc[3]));
    acc[4] = fmaf(p0, u2f_lo(z0.z), fmaf(p1, u2f_lo(z1.z), acc[4]));
    acc[5] = fmaf(p0, u2f_hi(z0.z), fmaf(p1, u2f_hi(z1.z), acc[5]));
    acc[6] = fmaf(p0, u2f_lo(z0.w), fmaf(p1, u2f_lo(z1.w), acc[6]));
    acc[7] = fmaf(p0, u2f_hi(z0.w), fmaf(p1, u2f_hi(z1.w), acc[7]));
  }
  if (e < end) {
    int sn = ssrc[e];
    uint4 zv = *reinterpret_cast<const uint4*>(T.z + (size_t)sn * F + lg * 8);
    float a = T.als[(size_t)sn * 8 + hh] + ad_h;
    a = a > 0.f ? a : 0.2f * a;
    float p = __expf(fminf(a, 30.f));
    den += p;
    acc[0] = fmaf(p, u2f_lo(zv.x), acc[0]);
    acc[1] = fmaf(p, u2f_hi(zv.x), acc[1]);
    acc[2] = fmaf(p, u2f_lo(zv.y), acc[2]);
    acc[3] = fmaf(p, u2f_hi(zv.y), acc[3]);
    acc[4] = fmaf(p, u2f_lo(zv.z), acc[4]);
    acc[5] = fmaf(p, u2f_hi(zv.z), acc[5]);
    acc[6] = fmaf(p, u2f_lo(zv.w), acc[6]);
    acc[7] = fmaf(p, u2f_hi(zv.w), acc[7]);
  }
  float inv = 1.f / fmaxf(den, 1e-16f);
  unsigned int pk[4];
#pragma unroll
  for (int k2 = 0; k2 < 4; k2++)
    pk[k2] = (unsigned int)f2b(fmaxf(acc[2*k2] * inv, 0.f))
           | ((unsigned int)f2b(fmaxf(acc[2*k2+1] * inv, 0.f)) << 16);
  *reinterpret_cast<uint4*>(T.out + (size_t)n * F + lg * 8)
      = make_uint4(pk[0], pk[1], pk[2], pk[3]);
}

// ---- semantic softmax (K=2) combine + LayerNorm + ReLU, 2 tasks, F=128 ----
__global__ __launch_bounds__(256) void combine2_k(
    const ushort* __restrict__ o00, const ushort* __restrict__ o01,
    const float* __restrict__ sc0, float invn0, ushort* __restrict__ out0, int N0,
    const ushort* __restrict__ o10, const ushort* __restrict__ o11,
    const float* __restrict__ sc1, float invn1, ushort* __restrict__ out1, int N1,
    const float* __restrict__ g, const float* __restrict__ bb)
{
  int c1 = (N0 + 3) / 4;
  int b = blockIdx.x;
  const ushort *o0, *o1; const float* sc; float invn; ushort* outp; int N, lb;
  if (b < c1) { o0=o00; o1=o01; sc=sc0; invn=invn0; outp=out0; N=N0; lb=b; }
  else        { o0=o10; o1=o11; sc=sc1; invn=invn1; outp=out1; N=N1; lb=b-c1; }
  int wv = threadIdx.x >> 6, lane = threadIdx.x & 63;
  int n = lb * 4 + wv;
  if (n >= N) return;
  float s0 = sc[0] * invn, s1 = sc[1] * invn;
  float mx = fmaxf(s0, s1);
  float e0 = __expf(s0 - mx), e1 = __expf(s1 - mx);
  float w0 = e0 / (e0 + e1), w1 = e1 / (e0 + e1);
  float x[2];
#pragma unroll
  for (int jj = 0; jj < 2; jj++) {
    int idx = lane + 64 * jj;
    x[jj] = w0 * b2f(o0[(size_t)n * 128 + idx]) + w1 * b2f(o1[(size_t)n * 128 + idx]);
  }
  float sum = x[0] + x[1];
#pragma unroll
  for (int o = 32; o > 0; o >>= 1) sum += __shfl_xor(sum, o);
  float mu = sum / 128.f;
  float vs = 0.f;
#pragma unroll
  for (int jj = 0; jj < 2; jj++) { float dd = x[jj] - mu; vs = fmaf(dd, dd, vs); }
#pragma unroll
  for (int o = 32; o > 0; o >>= 1) vs += __shfl_xor(vs, o);
  float rstd = rsqrtf(vs / 128.f + 1e-5f);
#pragma unroll
  for (int jj = 0; jj < 2; jj++) {
    int idx = lane + 64 * jj;
    float y = (x[jj] - mu) * rstd * g[idx] + bb[idx];
    outp[(size_t)n * 128 + idx] = f2b(fmaxf(y, 0.f));
  }
}

// ---- layer-2 combine + LN + ReLU + final linear [64]->[2], F=64 ----------
__global__ __launch_bounds__(256) void combine_final_k(
    const ushort* __restrict__ o0, const ushort* __restrict__ o1,
    const float* __restrict__ sc, float invn,
    const float* __restrict__ g, const float* __restrict__ bb,
    const float* __restrict__ lw, const float* __restrict__ lb,
    float* __restrict__ outp, int N)
{
  int wv = threadIdx.x >> 6, lane = threadIdx.x & 63;
  int n = blockIdx.x * 4 + wv;
  if (n >= N) return;
  float s0 = sc[0] * invn, s1 = sc[1] * invn;
  float mx = fmaxf(s0, s1);
  float e0 = __expf(s0 - mx), e1 = __expf(s1 - mx);
  float w0 = e0 / (e0 + e1), w1 = e1 / (e0 + e1);
  float x = w0 * b2f(o0[(size_t)n * 64 + lane]) + w1 * b2f(o1[(size_t)n * 64 + lane]);
  float sum = x;
#pragma unroll
  for (int o = 32; o > 0; o >>= 1) sum += __shfl_xor(sum, o);
  float mu = sum / 64.f;
  float dd = x - mu;
  float vs = dd * dd;
#pragma unroll
  for (int o = 32; o > 0; o >>= 1) vs += __shfl_xor(vs, o);
  float rstd = rsqrtf(vs / 64.f + 1e-5f);
  float y = fmaxf((x - mu) * rstd * g[lane] + bb[lane], 0.f);
  float p0 = y * lw[lane * 2 + 0];
  float p1 = y * lw[lane * 2 + 1];
#pragma unroll
  for (int o = 32; o > 0; o >>= 1) { p0 += __shfl_xor(p0, o); p1 += __shfl_xor(p1, o); }
  if (lane == 0) {
    outp[(size_t)n * 2 + 0] = p0 + lb[0];
    outp[(size_t)n * 2 + 1] = p1 + lb[1];
  }
}

extern "C" void kernel_launch(void* const* d_in, const int* in_sizes, int n_in,
                              void* d_out, int out_size, void* d_ws, size_t ws_size,
                              hipStream_t stream)
{
  (void)in_sizes; (void)n_in; (void)out_size;
  const float* x_a = (const float*)d_in[0];
  const float* x_t = (const float*)d_in[1];
  const int* eat_s = (const int*)d_in[2];
  const int* eat_d = (const int*)d_in[3];
  const int* eta_s = (const int*)d_in[4];
  const int* eta_d = (const int*)d_in[5];
  const int* eaa_s = (const int*)d_in[6];
  const int* eaa_d = (const int*)d_in[7];
  const int* ett_s = (const int*)d_in[8];
  const int* ett_d = (const int*)d_in[9];
  const float* W_a1 = (const float*)d_in[10]; const float* b_a1 = (const float*)d_in[11];
  const float* W_t1 = (const float*)d_in[12]; const float* b_t1 = (const float*)d_in[13];
  const float* as_at1 = (const float*)d_in[14]; const float* ad_at1 = (const float*)d_in[15];
  const float* as_ta1 = (const float*)d_in[16]; const float* ad_ta1 = (const float*)d_in[17];
  const float* as_aa1 = (const float*)d_in[18]; const float* ad_aa1 = (const float*)d_in[19];
  const float* as_tt1 = (const float*)d_in[20]; const float* ad_tt1 = (const float*)d_in[21];
  const float* k1_W = (const float*)d_in[22]; const float* k1_b = (const float*)d_in[23];
  const float* q1   = (const float*)d_in[24];
  const float* W_a2 = (const float*)d_in[25]; const float* b_a2 = (const float*)d_in[26];
  const float* W_t2 = (const float*)d_in[27]; const float* b_t2 = (const float*)d_in[28];
  const float* as_ta2 = (const float*)d_in[31]; const float* ad_ta2 = (const float*)d_in[32];
  const float* as_aa2 = (const float*)d_in[33]; const float* ad_aa2 = (const float*)d_in[34];
  const float* k2_W = (const float*)d_in[37]; const float* k2_b = (const float*)d_in[38];
  const float* q2   = (const float*)d_in[39];
  const float* ln1_g = (const float*)d_in[40]; const float* ln1_b = (const float*)d_in[41];
  const float* ln2_g = (const float*)d_in[42]; const float* ln2_b = (const float*)d_in[43];
  const float* lin_W = (const float*)d_in[44]; const float* lin_b = (const float*)d_in[45];

  char* ws = (char*)d_ws;
  size_t off = 0;
  auto alloc = [&](size_t bytes) {
    size_t o = off; off += (bytes + 255) & ~(size_t)255; return o;
  };
  size_t ZA1 = alloc((size_t)NA * HID * 2);     // bf16 z_a; layer2 za2 aliases
  size_t ZT1 = alloc((size_t)NT * HID * 2);     // bf16 z_t; layer2 zt2 aliases
  size_t OTA = alloc((size_t)NA * HID * 2);     // bf16 o_ta -> xa1 in-place
  size_t OAA = alloc((size_t)NA * HID * 2);     // bf16 o_aa; L2: ota2|oaa2 alias
  size_t OAT = alloc((size_t)NT * HID * 2);     // bf16 o_at -> xt1 in-place
  size_t OTT = alloc((size_t)NT * HID * 2);
  size_t A_AS_AT = alloc((size_t)NA * 8 * 4);
  size_t A_AD_TA = alloc((size_t)NA * 8 * 4);
  size_t A_AS_AA = alloc((size_t)NA * 8 * 4);
  size_t A_AD_AA = alloc((size_t)NA * 8 * 4);
  size_t A_T_D_AT = alloc((size_t)NT * 8 * 4);
  size_t A_T_S_TA = alloc((size_t)NT * 8 * 4);
  size_t A_T_S_TT = alloc((size_t)NT * 8 * 4);
  size_t A_T_D_TT = alloc((size_t)NT * 8 * 4);
  // sharded CSR build + compacted final CSR
  size_t RP8  = alloc(((size_t)NSH * NTOT + 1) * 4);
  size_t CUR8 = alloc((size_t)NSH * NTOT * 4);  // doubles as sharded hist
  size_t SSH  = alloc((size_t)ETOT * 4);
  size_t RP   = alloc((size_t)(NTOT + 1) * 4);
  size_t SS   = alloc((size_t)ETOT * 4);
  size_t BSM  = alloc(2048 * 4);
  size_t BSM2 = alloc(256 * 4);
  size_t SC   = alloc(256);                     // 6 score accumulators
  if (off > ws_size) return;                    // fail visibly

  ushort* za1 = (ushort*)(ws + ZA1);
  ushort* zt1 = (ushort*)(ws + ZT1);
  ushort* ota = (ushort*)(ws + OTA);
  ushort* oaa = (ushort*)(ws + OAA);
  ushort* oat = (ushort*)(ws + OAT);
  ushort* ott = (ushort*)(ws + OTT);
  float* aASAT = (float*)(ws + A_AS_AT);
  float* aADTA = (float*)(ws + A_AD_TA);
  float* aASAA = (float*)(ws + A_AS_AA);
  float* aADAA = (float*)(ws + A_AD_AA);
  float* aTDAT = (float*)(ws + A_T_D_AT);
  float* aTSTA = (float*)(ws + A_T_S_TA);
  float* aTSTT = (float*)(ws + A_T_S_TT);
  float* aTDTT = (float*)(ws + A_T_D_TT);
  int* rp8  = (int*)(ws + RP8);
  int* cur8 = (int*)(ws + CUR8);
  int* ssh  = (int*)(ws + SSH);
  int* rp   = (int*)(ws + RP);
  int* ssrc = (int*)(ws + SS);
  int* bsum = (int*)(ws + BSM);
  int* bsum2= (int*)(ws + BSM2);
  float* scp = (float*)(ws + SC);
  // layer-2 aliases
  ushort* za2 = za1;                                   // [NA,64] bf16
  ushort* zt2 = zt1;                                   // [NT,64] bf16
  ushort* ota2 = oaa;                                  // [NA,64] bf16
  ushort* oaa2 = (ushort*)(ws + OAA + (size_t)NA * OUTF * 2);  // [NA,64] bf16

  const int TA = (NA + 63) / 64, TT = (NT + 63) / 64;  // row tiles
  const int EBL = (ETOT + 255) / 256;
  const int SCN8 = NSH * NTOT;
  const int SBL8 = (SCN8 + 2047) / 2048;
  const int SBL1 = (NTOT + 2047) / 2048;
  const int NBL2 = (NTOT + 255) / 256;

  // ---- sharded CSR build + compact ----
  hipMemsetAsync(cur8, 0, (size_t)SCN8 * 4, stream);
  hist4_sh<<<EBL, 256, 0, stream>>>(eat_d, eta_d, eaa_d, ett_d, cur8, scp);
  scan_blk<<<SBL8, 256, 0, stream>>>(cur8, rp8 + 1, bsum, SCN8);
  scan_blk_sum8<<<SBL1, 256, 0, stream>>>(cur8, rp + 1, bsum2, NTOT);
  scan_two<<<2, 256, 0, stream>>>(bsum, SBL8, bsum2, SBL1);
  scan_addM<<<(SCN8 + 255) / 256, 256, 0, stream>>>(rp8, cur8, bsum, SCN8,
                                                    rp, bsum2, NTOT);
  scatter_sh<<<EBL, 256, 0, stream>>>(eat_s, eat_d, eta_s, eta_d,
                                      eaa_s, eaa_d, ett_s, ett_d, cur8, ssh);
  compact_k<<<NBL2, 256, 0, stream>>>(rp8, rp, ssh, ssrc);

  // ============ Layer 1 ============
  zgemm_k<4,16,FA,HID,2,float><<<(TA+1)/2,256,0,stream>>>(x_a, W_a1, b_a1,
      as_at1, ad_ta1, as_aa1, ad_aa1, aASAT, aADTA, aASAA, aADAA, za1, NA);
  zgemm_k<4,16,FT,HID,4,float><<<(TT+3)/4,256,0,stream>>>(x_t, W_t1, b_t1,
      ad_at1, as_ta1, as_tt1, ad_tt1, aTDAT, aTSTA, aTSTT, aTDTT, zt1, NT);
  {
    const int BT = (NT + 15) / 16, BA = (NA + 15) / 16;
    const int btot = BT + BA;
    const int grid = ((btot + 3) / 4) * 8;
    AggTask Tat{0,        NT, aASAT, aTDAT, za1, oat};
    AggTask Taa{NT+NA,    NA, aASAA, aADAA, za1, oaa};
    AggTask Tta{NT,       NA, aTSTA, aADTA, zt1, ota};
    AggTask Ttt{NT+2*NA,  NT, aTSTT, aTDTT, zt1, ott};
    agg_multi<128><<<grid, 256, 0, stream>>>(rp, ssrc,
        Tat, Taa, Tta, Ttt, BT, BA, btot);
  }
  {
    const int bA = (TA + 3) / 4, bT = (TT + 3) / 4;
    score_k<HID,HID,4><<<2*bA + 2*bT, 256, 0, stream>>>(ota, oaa, oat, ott,
        k1_W, k1_b, q1, scp,
        make_int4(bA, 2*bA, 2*bA + bT, 2*bA + 2*bT),
        make_int4(NA, NA, NT, NT));
  }
  combine2_k<<<(NA/4) + (NT/4), 256, 0, stream>>>(
      ota, oaa, scp + 0, 1.f/NA, ota, NA,
      oat, ott, scp + 2, 1.f/NT, oat, NT, ln1_g, ln1_b);

  // ============ Layer 2 (only the address path feeds the output) ============
  zgemm_k<3,8,HID,OUTF,2,ushort><<<(TA+1)/2,256,0,stream>>>(ota, W_a2, b_a2,
      ad_ta2, as_aa2, ad_aa2, nullptr, aADTA, aASAA, aADAA, nullptr, za2, NA);
  zgemm_k<1,8,HID,OUTF,4,ushort><<<(TT+3)/4,256,0,stream>>>(oat, W_t2, b_t2,
      as_ta2, nullptr, nullptr, nullptr, aTSTA, nullptr, nullptr, nullptr, zt2, NT);
  {
    const int BA2 = (NA + 31) / 32;
    const int grid = ((BA2 + 3) / 4) * 8;
    AggTask Taa2{NT+NA, NA, aASAA, aADAA, za2, oaa2};
    AggTask Tta2{NT,    NA, aTSTA, aADTA, zt2, ota2};
    agg_multi<64><<<grid, 256, 0, stream>>>(rp, ssrc,
        Taa2, Taa2, Tta2, Tta2, BA2, BA2, BA2);
  }
  {
    const int bA = (TA + 3) / 4;
    score_k<OUTF,OUTF,4><<<2*bA, 256, 0, stream>>>(ota2, oaa2, ota2, ota2,
        k2_W, k2_b, q2, scp + 4,
        make_int4(bA, 2*bA, 2*bA, 2*bA),
        make_int4(NA, NA, NA, NA));
  }
  combine_final_k<<<NA/4, 256, 0, stream>>>(ota2, oaa2, scp + 4, 1.f/NA,
      ln2_g, ln2_b, lin_W, lin_b, (float*)d_out, NA);
}